// Round 3
// baseline (2841.325 us; speedup 1.0000x reference)
//
#include <hip/hip_runtime.h>

typedef unsigned short u16;
typedef short s16x8 __attribute__((ext_vector_type(8)));
typedef float f32x4 __attribute__((ext_vector_type(4)));
typedef float f32x4u __attribute__((ext_vector_type(4), aligned(4)));
typedef unsigned short us4 __attribute__((ext_vector_type(4)));   // 8 B

__device__ __forceinline__ float bf2f(u16 v) {
    return __uint_as_float(((unsigned int)v) << 16);
}
__device__ __forceinline__ u16 f2bf(float f) {
    unsigned int u = __float_as_uint(f);
    u = u + 0x7FFFu + ((u >> 16) & 1u);
    return (u16)(u >> 16);
}
__device__ __forceinline__ f32x4 mfma16(s16x8 a, s16x8 b, f32x4 c) {
    return __builtin_amdgcn_mfma_f32_16x16x32_bf16(a, b, c, 0, 0, 0);
}
#define ZERO4 f32x4{0.f, 0.f, 0.f, 0.f}

// ---- grid barrier state (zero-initialized at module load; self-resetting) ----
__device__ __align__(128) unsigned g_cnt;
__device__ __align__(128) unsigned g_gen;

__device__ __forceinline__ void gbar(int nblk) {
    __syncthreads();
    if (threadIdx.x == 0) {
        __threadfence();
        unsigned g = __hip_atomic_load(&g_gen, __ATOMIC_RELAXED, __HIP_MEMORY_SCOPE_AGENT);
        unsigned a = __hip_atomic_fetch_add(&g_cnt, 1u, __ATOMIC_ACQ_REL, __HIP_MEMORY_SCOPE_AGENT);
        if (a == (unsigned)(nblk - 1)) {
            __hip_atomic_store(&g_cnt, 0u, __ATOMIC_RELAXED, __HIP_MEMORY_SCOPE_AGENT);
            __hip_atomic_store(&g_gen, g + 1u, __ATOMIC_RELEASE, __HIP_MEMORY_SCOPE_AGENT);
        } else {
            while (__hip_atomic_load(&g_gen, __ATOMIC_ACQUIRE, __HIP_MEMORY_SCOPE_AGENT) == g)
                __builtin_amdgcn_s_sleep(2);
        }
        __threadfence();
    }
    __syncthreads();
}

// ============ prepack: f32 weights -> bf16 MFMA B-fragment layouts ============
__global__ void prepack_kernel(const float* __restrict__ conv_w, const float* __restrict__ Wk,
                               const float* __restrict__ Wv, const float* __restrict__ Wq,
                               const float* __restrict__ W1, const float* __restrict__ W2,
                               u16* __restrict__ Bp, u16* __restrict__ WkvP, u16* __restrict__ WqP,
                               u16* __restrict__ W1T, u16* __restrict__ W2T)
{
    int idx = blockIdx.x * 256 + threadIdx.x;
    if (idx < 294912) {                       // 256 n * 1152 groups
        int n = idx / 1152, g = idx - n * 1152;
        int ic = g / 9, r = g - ic * 9;
        const float* s = conv_w + n * 3456 + ic * 27 + r * 3;
        u16* d = Bp + n * 4608 + g * 4;
        d[0] = f2bf(s[0]); d[1] = f2bf(s[1]); d[2] = f2bf(s[2]); d[3] = 0;
    } else if (idx < 425984) {                // WkvP 512*256
        int i = idx - 294912;
        int n = i >> 8, c = i & 255;
        WkvP[i] = f2bf((n < 256) ? Wk[c * 256 + n] : Wv[c * 256 + (n - 256)]);
    } else if (idx < 491520) {                // WqP 256*256
        int i = idx - 425984;
        int n = i >> 8, c = i & 255;
        WqP[i] = f2bf(Wq[c * 256 + n]);
    } else if (idx < 622592) {                // W1T 512*256
        int i = idx - 491520;
        int h = i >> 8, c = i & 255;
        W1T[i] = f2bf(W1[c * 512 + h]);
    } else if (idx < 753664) {                // W2T 256*512
        int i = idx - 622592;
        int dd = i >> 9, h = i & 511;
        W2T[i] = f2bf(W2[h * 256 + dd]);
    }
}

// ============ fused conv3d(s2)+bias+ReLU+LN_in + k/v GEMM ============
// grid 512 = b(8) * ox(16) * oyb(4); block 512 (8 waves); M-tile 64 tokens
__global__ __launch_bounds__(512, 4) void conv_fused(
    const float* __restrict__ x, const u16* __restrict__ Bp, const float* __restrict__ conv_b,
    const float* __restrict__ ln_g, const float* __restrict__ ln_b, const u16* __restrict__ WkvP,
    u16* __restrict__ kbuf, u16* __restrict__ vT)
{
    __shared__ __align__(16) char smem[38400];
    u16* slab   = (u16*)smem;                 // [432 rows][36 iz] u16 = 31104 B
    u16* tokbf  = (u16*)smem;                 // alias: [64 m][264 c] = 33792 B
    float* lnred  = (float*)(smem + 33792);   // [8 w][64 m][2] = 4096
    float* lnstat = (float*)(smem + 37888);   // [64 m][2] = 512

    int blk = blockIdx.x;
    int b = blk >> 6, ox = (blk >> 2) & 15, oyb = blk & 3;
    int tid = threadIdx.x, wid = tid >> 6, lane = tid & 63;
    int quad = lane >> 4, l15 = lane & 15;
    int nbase = wid * 32;                     // conv n-slice: 32 channels/wave

    f32x4 acc[4][2];
    #pragma unroll
    for (int i = 0; i < 4; ++i)
        #pragma unroll
        for (int j = 0; j < 2; ++j) acc[i][j] = ZERO4;

    const u16* bprow0 = Bp + (nbase + l15) * 4608 + quad * 8;
    const u16* bprow1 = bprow0 + 16 * 4608;

    for (int icc = 0; icc < 8; ++icc) {
        __syncthreads();
        // ---- staging: 432 rows x 9 float4-slots = 3888 slots, 8/thread ----
        {
            f32x4u tv[8];
            int so8[8];
            #pragma unroll
            for (int u = 0; u < 8; ++u) {
                int s = tid + u * 512;
                tv[u] = f32x4u{0.f, 0.f, 0.f, 0.f};
                so8[u] = -1;
                if (s < 3888) {
                    int row = s / 9;
                    int c = s - row * 9;
                    int icl = row / 27;
                    int rr = row - icl * 27;
                    int ixl = rr / 9;
                    int iyl = rr - ixl * 9;
                    const float* xr = x + ((size_t)((b * 128 + icc * 16 + icl) * 33)
                                           + (2 * ox + ixl)) * 1089 + (8 * oyb + iyl) * 33;
                    if (c < 8) tv[u] = *(const f32x4u*)(xr + c * 4);
                    else       tv[u].x = xr[32];          // iz 32; 33..35 stay 0
                    so8[u] = row * 36 + c * 4;
                }
            }
            #pragma unroll
            for (int u = 0; u < 8; ++u) {
                if (so8[u] >= 0) {
                    us4 w;
                    w.x = f2bf(tv[u].x); w.y = f2bf(tv[u].y);
                    w.z = f2bf(tv[u].z); w.w = f2bf(tv[u].w);
                    *(us4*)(slab + so8[u]) = w;
                }
            }
        }
        __syncthreads();

        const u16* bk0 = bprow0 + icc * 576;
        const u16* bk1 = bprow1 + icc * 576;
        s16x8 bbA[2], bbB[2];
        bbA[0] = *reinterpret_cast<const s16x8*>(bk0);
        bbA[1] = *reinterpret_cast<const s16x8*>(bk1);

#define CONV_STEP(CC, BREG)                                                     \
        {                                                                       \
            int g = (CC) * 8 + quad * 2;                                        \
            int i0 = g / 9, r9 = g - i0 * 9;                                    \
            int kx = r9 / 3, ky = r9 - kx * 3;                                  \
            int base0 = (i0 * 27 + kx * 9 + ky) * 36 + 2 * l15;                 \
            g += 1;                                                             \
            i0 = g / 9; r9 = g - i0 * 9; kx = r9 / 3; ky = r9 - kx * 3;         \
            int base1 = (i0 * 27 + kx * 9 + ky) * 36 + 2 * l15;                 \
            _Pragma("unroll")                                                   \
            for (int fm = 0; fm < 4; ++fm) {                                    \
                union { s16x8 v; ushort2 h[4]; } af;                            \
                const u16* sp0 = slab + base0 + fm * 72;                        \
                const u16* sp1 = slab + base1 + fm * 72;                        \
                af.h[0] = *(const ushort2*)(sp0);                               \
                af.h[1] = *(const ushort2*)(sp0 + 2);                           \
                af.h[2] = *(const ushort2*)(sp1);                               \
                af.h[3] = *(const ushort2*)(sp1 + 2);                           \
                acc[fm][0] = mfma16(af.v, (BREG)[0], acc[fm][0]);               \
                acc[fm][1] = mfma16(af.v, (BREG)[1], acc[fm][1]);               \
            }                                                                   \
        }

        #pragma unroll 1
        for (int c8 = 0; c8 < 18; c8 += 2) {
            bbB[0] = *reinterpret_cast<const s16x8*>(bk0 + (c8 + 1) * 32);
            bbB[1] = *reinterpret_cast<const s16x8*>(bk1 + (c8 + 1) * 32);
            CONV_STEP(c8, bbA)
            if (c8 + 2 < 18) {
                bbA[0] = *reinterpret_cast<const s16x8*>(bk0 + (c8 + 2) * 32);
                bbA[1] = *reinterpret_cast<const s16x8*>(bk1 + (c8 + 2) * 32);
            }
            CONV_STEP(c8 + 1, bbB)
        }
#undef CONV_STEP
    }
    // ---- bias + relu ----
    #pragma unroll
    for (int fn = 0; fn < 2; ++fn) {
        float bias = conv_b[nbase + fn * 16 + l15];
        #pragma unroll
        for (int fm = 0; fm < 4; ++fm)
            #pragma unroll
            for (int r = 0; r < 4; ++r)
                acc[fm][fn][r] = fmaxf(acc[fm][fn][r] + bias, 0.f);
    }
    // ---- LN_in ----
    #pragma unroll
    for (int fm = 0; fm < 4; ++fm) {
        #pragma unroll
        for (int r = 0; r < 4; ++r) {
            float s = acc[fm][0][r] + acc[fm][1][r];
            float q2 = acc[fm][0][r] * acc[fm][0][r] + acc[fm][1][r] * acc[fm][1][r];
            #pragma unroll
            for (int msk = 1; msk <= 8; msk <<= 1) {
                s  += __shfl_xor(s, msk, 64);
                q2 += __shfl_xor(q2, msk, 64);
            }
            if (l15 == 0) {
                int mm = fm * 16 + quad * 4 + r;
                lnred[(wid * 64 + mm) * 2 + 0] = s;
                lnred[(wid * 64 + mm) * 2 + 1] = q2;
            }
        }
    }
    __syncthreads();
    if (tid < 64) {
        float s = 0, q2 = 0;
        #pragma unroll
        for (int w = 0; w < 8; ++w) { s += lnred[(w * 64 + tid) * 2]; q2 += lnred[(w * 64 + tid) * 2 + 1]; }
        float mu = s * (1.f / 256.f);
        float var = fmaxf(q2 * (1.f / 256.f) - mu * mu, 0.f);
        lnstat[tid * 2]     = mu;
        lnstat[tid * 2 + 1] = rsqrtf(var + 1e-5f);
    }
    __syncthreads();
    {
        float gam[2], bet[2];
        #pragma unroll
        for (int fn = 0; fn < 2; ++fn) {
            int n = nbase + fn * 16 + l15;
            gam[fn] = ln_g[n]; bet[fn] = ln_b[n];
        }
        #pragma unroll
        for (int fm = 0; fm < 4; ++fm)
            #pragma unroll
            for (int r = 0; r < 4; ++r) {
                int mm = fm * 16 + quad * 4 + r;
                float mu = lnstat[mm * 2], rs = lnstat[mm * 2 + 1];
                #pragma unroll
                for (int fn = 0; fn < 2; ++fn) {
                    int n = nbase + fn * 16 + l15;
                    tokbf[mm * 264 + n] = f2bf((acc[fm][fn][r] - mu) * rs * gam[fn] + bet[fn]);
                }
            }
    }
    __syncthreads();
    // ---- k/v GEMM: [64 m]x[512 n], K=256; each wave owns 64 n for all m ----
    f32x4 kacc[4][4];
    #pragma unroll
    for (int i = 0; i < 4; ++i)
        #pragma unroll
        for (int j = 0; j < 4; ++j) kacc[i][j] = ZERO4;
    int n2 = wid * 64;
    const u16* wp = WkvP + (n2 + l15) * 256 + quad * 8;
    s16x8 wvA[4], wvB[4];
    #pragma unroll
    for (int fn = 0; fn < 4; ++fn) wvA[fn] = *reinterpret_cast<const s16x8*>(wp + fn * 4096);

#define KV_STEP(KK, WREG)                                                           \
    {                                                                               \
        s16x8 a2[4];                                                                \
        _Pragma("unroll")                                                           \
        for (int fm = 0; fm < 4; ++fm)                                              \
            a2[fm] = *reinterpret_cast<const s16x8*>(tokbf + (fm * 16 + l15) * 264  \
                                                     + (KK) * 32 + quad * 8);       \
        _Pragma("unroll")                                                           \
        for (int fn = 0; fn < 4; ++fn)                                              \
            _Pragma("unroll")                                                       \
            for (int fm = 0; fm < 4; ++fm)                                          \
                kacc[fm][fn] = mfma16(a2[fm], (WREG)[fn], kacc[fm][fn]);            \
    }

    #pragma unroll 1
    for (int kc = 0; kc < 8; kc += 2) {
        #pragma unroll
        for (int fn = 0; fn < 4; ++fn)
            wvB[fn] = *reinterpret_cast<const s16x8*>(wp + fn * 4096 + (kc + 1) * 32);
        KV_STEP(kc, wvA)
        if (kc + 2 < 8) {
            #pragma unroll
            for (int fn = 0; fn < 4; ++fn)
                wvA[fn] = *reinterpret_cast<const s16x8*>(wp + fn * 4096 + (kc + 2) * 32);
        }
        KV_STEP(kc + 1, wvB)
    }
#undef KV_STEP

    #pragma unroll
    for (int fm = 0; fm < 4; ++fm)
        #pragma unroll
        for (int r = 0; r < 4; ++r) {
            int l = (ox * 16 + oyb * 4 + fm) * 16 + quad * 4 + r;
            #pragma unroll
            for (int fn = 0; fn < 4; ++fn) {
                int n = n2 + fn * 16 + l15;
                u16 v = f2bf(kacc[fm][fn][r]);
                if (n < 256) kbuf[((b << 12) + l) * 256 + n] = v;           // k[b][l][d]
                else         vT[((b * 256 + (n - 256)) << 12) + l] = v;     // vT[b][d][l]
            }
        }
}

// ============ fused_iter: kQ + 6x(P ; barrier ; PVT ; barrier) + kE ============
// grid 256 x 512 threads; 1 block/CU -> always co-resident; hand grid barrier.
__global__ __launch_bounds__(512, 2) void fused_iter(
    const float* __restrict__ tinit, float* __restrict__ tpl,
    const float* __restrict__ ln_t_g, const float* __restrict__ ln_t_b,
    const float* __restrict__ ln_m_g, const float* __restrict__ ln_m_b,
    const u16* __restrict__ WqP, const u16* __restrict__ W1T, const float* __restrict__ b1,
    const u16* __restrict__ W2T, const float* __restrict__ b2,
    const u16* __restrict__ kbuf, const u16* __restrict__ vT,
    u16* __restrict__ qbuf, u16* __restrict__ attnT,
    float* __restrict__ cs_part, float* __restrict__ colsum,
    float* __restrict__ out0, float* __restrict__ out1)
{
    __shared__ __align__(16) char smem[46848];
    const int nblk = gridDim.x;
    int blk = blockIdx.x, tid = threadIdx.x;
    int wid = tid >> 6, lane = tid & 63;
    int quad = lane >> 4, l15 = lane & 15;

    // ================= kQ phase: init tpl, LN_t, q (iter 0) — blocks 0-7 =================
    if (blk < 8) {
        u16* mlsQ = (u16*)smem;                        // [64][264] = 33792
        float* plsQ = (float*)(smem + 33792);          // [64][8][2] = 4096
        float* statQ = (float*)(smem + 37888);         // [64][2] = 512
        int b = blk;
        int m = tid >> 3, part = tid & 7;
        const float* tp = tinit + m * 256 + part * 32;
        float* tg = tpl + (b * 64 + m) * 256 + part * 32;
        float s = 0, q2 = 0;
        #pragma unroll
        for (int i = 0; i < 32; ++i) {
            float v = tp[i];
            tg[i] = v;
            s += v; q2 += v * v;
        }
        plsQ[(m * 8 + part) * 2 + 0] = s; plsQ[(m * 8 + part) * 2 + 1] = q2;
        __syncthreads();
        if (tid < 64) {
            float ss = 0, qq = 0;
            #pragma unroll
            for (int p = 0; p < 8; ++p) { ss += plsQ[(tid * 8 + p) * 2]; qq += plsQ[(tid * 8 + p) * 2 + 1]; }
            float mu = ss * (1.f / 256.f);
            float var = fmaxf(qq * (1.f / 256.f) - mu * mu, 0.f);
            statQ[tid * 2] = mu; statQ[tid * 2 + 1] = rsqrtf(var + 1e-5f);
        }
        __syncthreads();
        {
            float mu = statQ[m * 2], rs = statQ[m * 2 + 1];
            #pragma unroll
            for (int i = 0; i < 32; ++i) {
                int d = part * 32 + i;
                mlsQ[m * 264 + d] = f2bf((tp[i] - mu) * rs * ln_t_g[d] + ln_t_b[d]);
            }
        }
        __syncthreads();
        // q-GEMM: 8 waves, wave -> 32-d slice (fn<2), fm<4 over 64 m
        f32x4 qa[4][2];
        #pragma unroll
        for (int i = 0; i < 4; ++i)
            #pragma unroll
            for (int j = 0; j < 2; ++j) qa[i][j] = ZERO4;
        #pragma unroll 1
        for (int kc = 0; kc < 8; ++kc) {
            s16x8 a[4];
            #pragma unroll
            for (int fm = 0; fm < 4; ++fm)
                a[fm] = *reinterpret_cast<const s16x8*>(mlsQ + (fm * 16 + l15) * 264 + kc * 32 + quad * 8);
            #pragma unroll
            for (int fn = 0; fn < 2; ++fn) {
                s16x8 bv = *reinterpret_cast<const s16x8*>(WqP + (wid * 32 + fn * 16 + l15) * 256 + kc * 32 + quad * 8);
                #pragma unroll
                for (int fm = 0; fm < 4; ++fm)
                    qa[fm][fn] = mfma16(a[fm], bv, qa[fm][fn]);
            }
        }
        #pragma unroll
        for (int fm = 0; fm < 4; ++fm)
            #pragma unroll
            for (int fn = 0; fn < 2; ++fn)
                #pragma unroll
                for (int r = 0; r < 4; ++r) {
                    int mt = fm * 16 + quad * 4 + r;
                    int d = wid * 32 + fn * 16 + l15;
                    qbuf[(b * 64 + mt) * 256 + d] = f2bf(qa[fm][fn][r] * 0.0625f);
                }
    }
    gbar(nblk);

    // ================= iteration loop =================
    for (int it = 0; it < 6; ++it) {
        int last = (it == 5) ? 1 : 0;
        // ---------- P phase: logits+softmax -> attnT + cs_part (all 256 blocks) ----------
        {
            u16* atile = (u16*)smem;                   // [64][136] = 17408
            float* colsh = (float*)(smem + 17408);     // [8][64] = 2048
            int b = blk >> 5, ltg = blk & 31;
            const u16* qb = qbuf + b * 16384;
            int lrow = ltg * 128 + wid * 16;
            const u16* arow = kbuf + (size_t)((b << 12) + lrow + l15) * 256;
            f32x4 sa[4];
            #pragma unroll
            for (int fn = 0; fn < 4; ++fn) sa[fn] = ZERO4;
            #pragma unroll 1
            for (int kc = 0; kc < 8; ++kc) {
                s16x8 a = *reinterpret_cast<const s16x8*>(arow + kc * 32 + quad * 8);
                #pragma unroll
                for (int fn = 0; fn < 4; ++fn) {
                    s16x8 bv = *reinterpret_cast<const s16x8*>(qb + (fn * 16 + l15) * 256 + kc * 32 + quad * 8);
                    sa[fn] = mfma16(a, bv, sa[fn]);
                }
            }
            float colp[4] = {0.f, 0.f, 0.f, 0.f};
            #pragma unroll
            for (int r = 0; r < 4; ++r) {
                float mx = fmaxf(fmaxf(sa[0][r], sa[1][r]), fmaxf(sa[2][r], sa[3][r]));
                #pragma unroll
                for (int msk = 1; msk <= 8; msk <<= 1) mx = fmaxf(mx, __shfl_xor(mx, msk, 64));
                float e[4], sum = 0;
                #pragma unroll
                for (int fn = 0; fn < 4; ++fn) { e[fn] = __expf(sa[fn][r] - mx); sum += e[fn]; }
                #pragma unroll
                for (int msk = 1; msk <= 8; msk <<= 1) sum += __shfl_xor(sum, msk, 64);
                float inv = 1.f / sum;
                #pragma unroll
                for (int fn = 0; fn < 4; ++fn) {
                    float p = e[fn] * inv + 1e-8f;
                    colp[fn] += p;
                    atile[(fn * 16 + l15) * 136 + wid * 16 + quad * 4 + r] = f2bf(p);
                }
            }
            #pragma unroll
            for (int fn = 0; fn < 4; ++fn) {
                float c = colp[fn];
                c += __shfl_xor(c, 16, 64);
                c += __shfl_xor(c, 32, 64);
                if (lane < 16) colsh[wid * 64 + fn * 16 + lane] = c;
            }
            __syncthreads();
            if (tid < 64) {
                float s = 0;
                #pragma unroll
                for (int w = 0; w < 8; ++w) s += colsh[w * 64 + tid];
                cs_part[((b << 5) + ltg) * 64 + tid] = s;
            }
            {
                int n = tid >> 3, lo = (tid & 7) * 16;
                const u16* src = atile + n * 136 + lo;
                u16* dst = attnT + (size_t)((b * 64 + n) << 12) + ltg * 128 + lo;
                *(int4*)(dst)     = *(const int4*)(src);
                *(int4*)(dst + 8) = *(const int4*)(src + 8);
            }
        }
        gbar(nblk);

        // ---------- PVT phase: PV (K=4096, regs) + LN_m + MLP + LN_t + q — blocks 0-31 ----------
        if (blk < 32) {
            float* dsh  = (float*)smem;                // [16][256] = 16384
            u16* mls    = (u16*)(smem + 16384);        // [16][264] = 8448
            u16* hid    = (u16*)(smem + 24832);        // [16][520] = 16640
            float* pls  = (float*)(smem + 41472);      // [16][32][2] = 4096
            float* stat = (float*)(smem + 45568);      // [16][2] = 128
            float* lnr2 = (float*)(smem + 45696);      // [8][16][2] = 1024
            float* cshT = (float*)(smem + 46720);      // [16] = 64
            int b = blk >> 2, mg = blk & 3, m0 = mg * 16;
            // colsum partials reduce
            if (tid < 16) {
                float s = 0;
                #pragma unroll
                for (int g = 0; g < 32; ++g) s += cs_part[((b << 5) + g) * 64 + m0 + tid];
                cshT[tid] = 1.f / s;
                if (last) colsum[b * 64 + m0 + tid] = s;
            }
            // ---- PV: delta[16n][256d] via regs; wave -> 32-d slice, full K=4096 ----
            {
                const u16* prow = attnT + ((size_t)(b * 64 + m0 + l15) << 12) + quad * 8;
                const u16* vrow = vT + ((size_t)(b * 256 + wid * 32 + l15) << 12) + quad * 8;
                f32x4 pacc[2];
                pacc[0] = ZERO4; pacc[1] = ZERO4;
                #pragma unroll 2
                for (int kc = 0; kc < 128; ++kc) {
                    s16x8 a  = *reinterpret_cast<const s16x8*>(prow + kc * 32);
                    s16x8 b0 = *reinterpret_cast<const s16x8*>(vrow + kc * 32);
                    s16x8 b1 = *reinterpret_cast<const s16x8*>(vrow + (16 << 12) + kc * 32);
                    pacc[0] = mfma16(a, b0, pacc[0]);
                    pacc[1] = mfma16(a, b1, pacc[1]);
                }
                #pragma unroll
                for (int fn = 0; fn < 2; ++fn)
                    #pragma unroll
                    for (int r = 0; r < 4; ++r)
                        dsh[(quad * 4 + r) * 256 + wid * 32 + fn * 16 + l15] = pacc[fn][r];
            }
            __syncthreads();
            // ---- phase1: v = tpl + delta/colsum; LN_m -> mls; tpl = v ----
            {
                int ml = tid >> 5, part = tid & 31;
                float cinv = cshT[ml];
                float* tg = tpl + (b * 64 + m0 + ml) * 256 + part * 8;
                float vbuf[8];
                float s = 0, q2 = 0;
                #pragma unroll
                for (int i = 0; i < 8; ++i) {
                    float v = tg[i] + dsh[ml * 256 + part * 8 + i] * cinv;
                    vbuf[i] = v; s += v; q2 += v * v;
                }
                pls[(ml * 32 + part) * 2 + 0] = s; pls[(ml * 32 + part) * 2 + 1] = q2;
                __syncthreads();
                if (tid < 16) {
                    float ss = 0, qq = 0;
                    #pragma unroll
                    for (int p = 0; p < 32; ++p) { ss += pls[(tid * 32 + p) * 2]; qq += pls[(tid * 32 + p) * 2 + 1]; }
                    float mu = ss * (1.f / 256.f);
                    float var = fmaxf(qq * (1.f / 256.f) - mu * mu, 0.f);
                    stat[tid * 2] = mu; stat[tid * 2 + 1] = rsqrtf(var + 1e-5f);
                }
                __syncthreads();
                float mu = stat[ml * 2], rs = stat[ml * 2 + 1];
                #pragma unroll
                for (int i = 0; i < 8; ++i) {
                    int d = part * 8 + i;
                    tg[i] = vbuf[i];
                    mls[ml * 264 + d] = f2bf((vbuf[i] - mu) * rs * ln_m_g[d] + ln_m_b[d]);
                }
            }
            __syncthreads();
            // ---- G1: hid = gelu(mls @ W1 + b1); wave -> 64 nh (fn<4) ----
            {
                f32x4 ha[4];
                #pragma unroll
                for (int j = 0; j < 4; ++j) ha[j] = ZERO4;
                #pragma unroll 1
                for (int kc = 0; kc < 8; ++kc) {
                    s16x8 a = *reinterpret_cast<const s16x8*>(mls + l15 * 264 + kc * 32 + quad * 8);
                    #pragma unroll
                    for (int fn = 0; fn < 4; ++fn) {
                        s16x8 bv = *reinterpret_cast<const s16x8*>(W1T + (wid * 64 + fn * 16 + l15) * 256 + kc * 32 + quad * 8);
                        ha[fn] = mfma16(a, bv, ha[fn]);
                    }
                }
                #pragma unroll
                for (int fn = 0; fn < 4; ++fn) {
                    int nh = wid * 64 + fn * 16 + l15;
                    float bb = b1[nh];
                    #pragma unroll
                    for (int r = 0; r < 4; ++r) {
                        float v = ha[fn][r] + bb;
                        v = 0.5f * v * (1.f + erff(v * 0.70710678118654752f));
                        hid[(quad * 4 + r) * 520 + nh] = f2bf(v);
                    }
                }
            }
            __syncthreads();
            // ---- G2: new = tpl + hid @ W2 + b2; LN_t; out0/mls ----
            {
                f32x4 oa[2];
                oa[0] = ZERO4; oa[1] = ZERO4;
                #pragma unroll 1
                for (int kc = 0; kc < 16; ++kc) {
                    s16x8 a = *reinterpret_cast<const s16x8*>(hid + l15 * 520 + kc * 32 + quad * 8);
                    #pragma unroll
                    for (int fn = 0; fn < 2; ++fn) {
                        s16x8 bv = *reinterpret_cast<const s16x8*>(W2T + (wid * 32 + fn * 16 + l15) * 512 + kc * 32 + quad * 8);
                        oa[fn] = mfma16(a, bv, oa[fn]);
                    }
                }
                #pragma unroll
                for (int fn = 0; fn < 2; ++fn) {
                    int d = wid * 32 + fn * 16 + l15;
                    float bb = b2[d];
                    #pragma unroll
                    for (int r = 0; r < 4; ++r) {
                        int mm = quad * 4 + r;
                        oa[fn][r] += bb + tpl[(b * 64 + m0 + mm) * 256 + d];
                    }
                }
                // LN_t stats: per row, partial over this wave's 32 d
                #pragma unroll
                for (int r = 0; r < 4; ++r) {
                    float s = oa[0][r] + oa[1][r];
                    float q2 = oa[0][r] * oa[0][r] + oa[1][r] * oa[1][r];
                    #pragma unroll
                    for (int msk = 1; msk <= 8; msk <<= 1) {
                        s  += __shfl_xor(s, msk, 64);
                        q2 += __shfl_xor(q2, msk, 64);
                    }
                    if (l15 == 0) {
                        lnr2[(wid * 16 + quad * 4 + r) * 2 + 0] = s;
                        lnr2[(wid * 16 + quad * 4 + r) * 2 + 1] = q2;
                    }
                }
                __syncthreads();
                if (tid < 16) {
                    float ss = 0, qq = 0;
                    #pragma unroll
                    for (int w = 0; w < 8; ++w) { ss += lnr2[(w * 16 + tid) * 2]; qq += lnr2[(w * 16 + tid) * 2 + 1]; }
                    float mu = ss * (1.f / 256.f);
                    float var = fmaxf(qq * (1.f / 256.f) - mu * mu, 0.f);
                    stat[tid * 2] = mu; stat[tid * 2 + 1] = rsqrtf(var + 1e-5f);
                }
                __syncthreads();
                #pragma unroll
                for (int fn = 0; fn < 2; ++fn) {
                    int d = wid * 32 + fn * 16 + l15;
                    float gg = last ? 0.f : ln_t_g[d];
                    float bt = last ? 0.f : ln_t_b[d];
                    #pragma unroll
                    for (int r = 0; r < 4; ++r) {
                        int mm = quad * 4 + r;
                        float v = oa[fn][r];
                        tpl[(b * 64 + m0 + mm) * 256 + d] = v;
                        if (last) {
                            out0[(b * 256 + d) * 64 + m0 + mm] = v;
                        } else {
                            mls[mm * 264 + d] = f2bf((v - stat[mm * 2]) * stat[mm * 2 + 1] * gg + bt);
                        }
                    }
                }
            }
            if (!last) {
                __syncthreads();
                // ---- q-GEMM for next iteration: wave -> 32-d slice ----
                f32x4 qa[2];
                qa[0] = ZERO4; qa[1] = ZERO4;
                #pragma unroll 1
                for (int kc = 0; kc < 8; ++kc) {
                    s16x8 a = *reinterpret_cast<const s16x8*>(mls + l15 * 264 + kc * 32 + quad * 8);
                    #pragma unroll
                    for (int fn = 0; fn < 2; ++fn) {
                        s16x8 bv = *reinterpret_cast<const s16x8*>(WqP + (wid * 32 + fn * 16 + l15) * 256 + kc * 32 + quad * 8);
                        qa[fn] = mfma16(a, bv, qa[fn]);
                    }
                }
                #pragma unroll
                for (int fn = 0; fn < 2; ++fn)
                    #pragma unroll
                    for (int r = 0; r < 4; ++r) {
                        int mt = m0 + quad * 4 + r;
                        int d = wid * 32 + fn * 16 + l15;
                        qbuf[(b * 64 + mt) * 256 + d] = f2bf(qa[fn][r] * 0.0625f);
                    }
            }
        }
        gbar(nblk);
    }

    // ================= kE phase: attn_out = attnT / colsum (all blocks) =================
    {
        #pragma unroll
        for (int j = 0; j < 4; ++j) {
            int idx = blk * 512 + tid + j * 131072;      // < 524288
            int e = idx * 4;
            int b = e >> 18, n = (e >> 12) & 63;
            float ci = 1.f / colsum[b * 64 + n];
            const u16* s = attnT + e;
            f32x4 o;
            o.x = bf2f(s[0]) * ci; o.y = bf2f(s[1]) * ci;
            o.z = bf2f(s[2]) * ci; o.w = bf2f(s[3]) * ci;
            *(f32x4*)(out1 + e) = o;
        }
    }
}

// ============ launch ============
extern "C" void kernel_launch(void* const* d_in, const int* in_sizes, int n_in,
                              void* d_out, int out_size, void* d_ws, size_t ws_size,
                              hipStream_t stream)
{
    const float* x       = (const float*)d_in[0];
    const float* tinit   = (const float*)d_in[1];
    const float* conv_w  = (const float*)d_in[2];
    const float* conv_b  = (const float*)d_in[3];
    const float* Wq      = (const float*)d_in[4];
    const float* Wk      = (const float*)d_in[5];
    const float* Wv      = (const float*)d_in[6];
    const float* ln_in_g = (const float*)d_in[7];
    const float* ln_in_b = (const float*)d_in[8];
    const float* ln_t_g  = (const float*)d_in[9];
    const float* ln_t_b  = (const float*)d_in[10];
    const float* ln_m_g  = (const float*)d_in[11];
    const float* ln_m_b  = (const float*)d_in[12];
    const float* W1      = (const float*)d_in[13];
    const float* b1      = (const float*)d_in[14];
    const float* W2      = (const float*)d_in[15];
    const float* b2      = (const float*)d_in[16];

    char* ws = (char*)d_ws;
    u16* Bp       = (u16*)(ws + 0);          // 2,359,296
    u16* WkvP     = (u16*)(ws + 2359296);    //   262,144
    u16* WqP      = (u16*)(ws + 2621440);    //   131,072
    u16* W1T      = (u16*)(ws + 2752512);    //   262,144
    u16* W2T      = (u16*)(ws + 3014656);    //   262,144
    u16* kbuf     = (u16*)(ws + 3276800);    // 16,777,216
    u16* vT       = (u16*)(ws + 20054016);   // 16,777,216
    u16* qbuf     = (u16*)(ws + 36831232);   //   262,144
    u16* attnT    = (u16*)(ws + 37093376);   // 4,194,304  (P every iter; attn out last)
    float* colsum = (float*)(ws + 41287680); //     2,048
    float* tpl    = (float*)(ws + 41289728); //   524,288
    float* cs_part= (float*)(ws + 41814016); //    65,536   (total ~41.9 MB)

    float* out0 = (float*)d_out;      // templates_out (8,256,64)
    float* out1 = out0 + 131072;      // attn_out (8,64,16,16,16)

    prepack_kernel<<<2944, 256, 0, stream>>>(conv_w, Wk, Wv, Wq, W1, W2, Bp, WkvP, WqP, W1T, W2T);
    conv_fused<<<512, 512, 0, stream>>>(x, Bp, conv_b, ln_in_g, ln_in_b, WkvP, kbuf, vT);
    fused_iter<<<256, 512, 0, stream>>>(tinit, tpl, ln_t_g, ln_t_b, ln_m_g, ln_m_b,
                                        WqP, W1T, b1, W2T, b2, kbuf, vT,
                                        qbuf, attnT, cs_part, colsum, out0, out1);
}

// Round 4
// 806.291 us; speedup vs baseline: 3.5239x; 3.5239x over previous
//
#include <hip/hip_runtime.h>

typedef unsigned short u16;
typedef short s16x8 __attribute__((ext_vector_type(8)));
typedef float f32x4 __attribute__((ext_vector_type(4)));
typedef float f32x4u __attribute__((ext_vector_type(4), aligned(4)));
typedef unsigned short us4 __attribute__((ext_vector_type(4)));   // 8 B

__device__ __forceinline__ float bf2f(u16 v) {
    return __uint_as_float(((unsigned int)v) << 16);
}
__device__ __forceinline__ u16 f2bf(float f) {
    unsigned int u = __float_as_uint(f);
    u = u + 0x7FFFu + ((u >> 16) & 1u);
    return (u16)(u >> 16);
}
__device__ __forceinline__ f32x4 mfma16(s16x8 a, s16x8 b, f32x4 c) {
    return __builtin_amdgcn_mfma_f32_16x16x32_bf16(a, b, c, 0, 0, 0);
}
#define ZERO4 f32x4{0.f, 0.f, 0.f, 0.f}

// ============ prepack: f32 weights -> bf16 MFMA B-fragment layouts ============
__global__ void prepack_kernel(const float* __restrict__ conv_w, const float* __restrict__ Wk,
                               const float* __restrict__ Wv, const float* __restrict__ Wq,
                               const float* __restrict__ W1, const float* __restrict__ W2,
                               u16* __restrict__ Bp, u16* __restrict__ WkvP, u16* __restrict__ WqP,
                               u16* __restrict__ W1T, u16* __restrict__ W2T)
{
    int idx = blockIdx.x * 256 + threadIdx.x;
    if (idx < 294912) {                       // 256 n * 1152 groups
        int n = idx / 1152, g = idx - n * 1152;
        int ic = g / 9, r = g - ic * 9;
        const float* s = conv_w + n * 3456 + ic * 27 + r * 3;
        u16* d = Bp + n * 4608 + g * 4;
        d[0] = f2bf(s[0]); d[1] = f2bf(s[1]); d[2] = f2bf(s[2]); d[3] = 0;
    } else if (idx < 425984) {                // WkvP 512*256
        int i = idx - 294912;
        int n = i >> 8, c = i & 255;
        WkvP[i] = f2bf((n < 256) ? Wk[c * 256 + n] : Wv[c * 256 + (n - 256)]);
    } else if (idx < 491520) {                // WqP 256*256
        int i = idx - 425984;
        int n = i >> 8, c = i & 255;
        WqP[i] = f2bf(Wq[c * 256 + n]);
    } else if (idx < 622592) {                // W1T 512*256
        int i = idx - 491520;
        int h = i >> 8, c = i & 255;
        W1T[i] = f2bf(W1[c * 512 + h]);
    } else if (idx < 753664) {                // W2T 256*512
        int i = idx - 622592;
        int dd = i >> 9, h = i & 511;
        W2T[i] = f2bf(W2[h * 256 + dd]);
    }
}

// ============ fused conv3d(s2)+bias+ReLU+LN_in + k/v GEMM ============
// grid 512; b = blk&7 (XCD-pinned: all blocks of batch b on XCD b); block 512 (8 waves)
__global__ __launch_bounds__(512, 4) void conv_fused(
    const float* __restrict__ x, const u16* __restrict__ Bp, const float* __restrict__ conv_b,
    const float* __restrict__ ln_g, const float* __restrict__ ln_b, const u16* __restrict__ WkvP,
    u16* __restrict__ kbuf, u16* __restrict__ vT)
{
    __shared__ __align__(16) char smem[38400];
    u16* slab   = (u16*)smem;                 // [432 rows][36 iz] u16 = 31104 B
    u16* tokbf  = (u16*)smem;                 // alias: [64 m][264 c] = 33792 B
    float* lnred  = (float*)(smem + 33792);   // [8 w][64 m][2] = 4096
    float* lnstat = (float*)(smem + 37888);   // [64 m][2] = 512

    int blk = blockIdx.x;
    int b = blk & 7, ox = (blk >> 5) & 15, oyb = (blk >> 3) & 3;   // XCD pin: b = blk%8
    int tid = threadIdx.x, wid = tid >> 6, lane = tid & 63;
    int quad = lane >> 4, l15 = lane & 15;
    int nbase = wid * 32;                     // conv n-slice: 32 channels/wave

    f32x4 acc[4][2];
    #pragma unroll
    for (int i = 0; i < 4; ++i)
        #pragma unroll
        for (int j = 0; j < 2; ++j) acc[i][j] = ZERO4;

    const u16* bprow0 = Bp + (nbase + l15) * 4608 + quad * 8;
    const u16* bprow1 = bprow0 + 16 * 4608;

    for (int icc = 0; icc < 8; ++icc) {
        __syncthreads();
        // ---- staging: 432 rows x 9 float4-slots = 3888 slots, 8/thread ----
        {
            f32x4u tv[8];
            int so8[8];
            #pragma unroll
            for (int u = 0; u < 8; ++u) {
                int s = tid + u * 512;
                tv[u] = f32x4u{0.f, 0.f, 0.f, 0.f};
                so8[u] = -1;
                if (s < 3888) {
                    int row = s / 9;
                    int c = s - row * 9;
                    int icl = row / 27;
                    int rr = row - icl * 27;
                    int ixl = rr / 9;
                    int iyl = rr - ixl * 9;
                    const float* xr = x + ((size_t)((b * 128 + icc * 16 + icl) * 33)
                                           + (2 * ox + ixl)) * 1089 + (8 * oyb + iyl) * 33;
                    if (c < 8) tv[u] = *(const f32x4u*)(xr + c * 4);
                    else       tv[u].x = xr[32];          // iz 32; 33..35 stay 0
                    so8[u] = row * 36 + c * 4;
                }
            }
            #pragma unroll
            for (int u = 0; u < 8; ++u) {
                if (so8[u] >= 0) {
                    us4 w;
                    w.x = f2bf(tv[u].x); w.y = f2bf(tv[u].y);
                    w.z = f2bf(tv[u].z); w.w = f2bf(tv[u].w);
                    *(us4*)(slab + so8[u]) = w;
                }
            }
        }
        __syncthreads();

        const u16* bk0 = bprow0 + icc * 576;
        const u16* bk1 = bprow1 + icc * 576;
        s16x8 bbA[2], bbB[2];
        bbA[0] = *reinterpret_cast<const s16x8*>(bk0);
        bbA[1] = *reinterpret_cast<const s16x8*>(bk1);

#define CONV_STEP(CC, BREG)                                                     \
        {                                                                       \
            int g = (CC) * 8 + quad * 2;                                        \
            int i0 = g / 9, r9 = g - i0 * 9;                                    \
            int kx = r9 / 3, ky = r9 - kx * 3;                                  \
            int base0 = (i0 * 27 + kx * 9 + ky) * 36 + 2 * l15;                 \
            g += 1;                                                             \
            i0 = g / 9; r9 = g - i0 * 9; kx = r9 / 3; ky = r9 - kx * 3;         \
            int base1 = (i0 * 27 + kx * 9 + ky) * 36 + 2 * l15;                 \
            _Pragma("unroll")                                                   \
            for (int fm = 0; fm < 4; ++fm) {                                    \
                union { s16x8 v; ushort2 h[4]; } af;                            \
                const u16* sp0 = slab + base0 + fm * 72;                        \
                const u16* sp1 = slab + base1 + fm * 72;                        \
                af.h[0] = *(const ushort2*)(sp0);                               \
                af.h[1] = *(const ushort2*)(sp0 + 2);                           \
                af.h[2] = *(const ushort2*)(sp1);                               \
                af.h[3] = *(const ushort2*)(sp1 + 2);                           \
                acc[fm][0] = mfma16(af.v, (BREG)[0], acc[fm][0]);               \
                acc[fm][1] = mfma16(af.v, (BREG)[1], acc[fm][1]);               \
            }                                                                   \
        }

        #pragma unroll 1
        for (int c8 = 0; c8 < 18; c8 += 2) {
            bbB[0] = *reinterpret_cast<const s16x8*>(bk0 + (c8 + 1) * 32);
            bbB[1] = *reinterpret_cast<const s16x8*>(bk1 + (c8 + 1) * 32);
            CONV_STEP(c8, bbA)
            if (c8 + 2 < 18) {
                bbA[0] = *reinterpret_cast<const s16x8*>(bk0 + (c8 + 2) * 32);
                bbA[1] = *reinterpret_cast<const s16x8*>(bk1 + (c8 + 2) * 32);
            }
            CONV_STEP(c8 + 1, bbB)
        }
#undef CONV_STEP
    }
    // ---- bias + relu ----
    #pragma unroll
    for (int fn = 0; fn < 2; ++fn) {
        float bias = conv_b[nbase + fn * 16 + l15];
        #pragma unroll
        for (int fm = 0; fm < 4; ++fm)
            #pragma unroll
            for (int r = 0; r < 4; ++r)
                acc[fm][fn][r] = fmaxf(acc[fm][fn][r] + bias, 0.f);
    }
    // ---- LN_in ----
    #pragma unroll
    for (int fm = 0; fm < 4; ++fm) {
        #pragma unroll
        for (int r = 0; r < 4; ++r) {
            float s = acc[fm][0][r] + acc[fm][1][r];
            float q2 = acc[fm][0][r] * acc[fm][0][r] + acc[fm][1][r] * acc[fm][1][r];
            #pragma unroll
            for (int msk = 1; msk <= 8; msk <<= 1) {
                s  += __shfl_xor(s, msk, 64);
                q2 += __shfl_xor(q2, msk, 64);
            }
            if (l15 == 0) {
                int mm = fm * 16 + quad * 4 + r;
                lnred[(wid * 64 + mm) * 2 + 0] = s;
                lnred[(wid * 64 + mm) * 2 + 1] = q2;
            }
        }
    }
    __syncthreads();
    if (tid < 64) {
        float s = 0, q2 = 0;
        #pragma unroll
        for (int w = 0; w < 8; ++w) { s += lnred[(w * 64 + tid) * 2]; q2 += lnred[(w * 64 + tid) * 2 + 1]; }
        float mu = s * (1.f / 256.f);
        float var = fmaxf(q2 * (1.f / 256.f) - mu * mu, 0.f);
        lnstat[tid * 2]     = mu;
        lnstat[tid * 2 + 1] = rsqrtf(var + 1e-5f);
    }
    __syncthreads();
    {
        float gam[2], bet[2];
        #pragma unroll
        for (int fn = 0; fn < 2; ++fn) {
            int n = nbase + fn * 16 + l15;
            gam[fn] = ln_g[n]; bet[fn] = ln_b[n];
        }
        #pragma unroll
        for (int fm = 0; fm < 4; ++fm)
            #pragma unroll
            for (int r = 0; r < 4; ++r) {
                int mm = fm * 16 + quad * 4 + r;
                float mu = lnstat[mm * 2], rs = lnstat[mm * 2 + 1];
                #pragma unroll
                for (int fn = 0; fn < 2; ++fn) {
                    int n = nbase + fn * 16 + l15;
                    tokbf[mm * 264 + n] = f2bf((acc[fm][fn][r] - mu) * rs * gam[fn] + bet[fn]);
                }
            }
    }
    __syncthreads();
    // ---- k/v GEMM: [64 m]x[512 n], K=256; each wave owns 64 n for all m ----
    f32x4 kacc[4][4];
    #pragma unroll
    for (int i = 0; i < 4; ++i)
        #pragma unroll
        for (int j = 0; j < 4; ++j) kacc[i][j] = ZERO4;
    int n2 = wid * 64;
    const u16* wp = WkvP + (n2 + l15) * 256 + quad * 8;
    s16x8 wvA[4], wvB[4];
    #pragma unroll
    for (int fn = 0; fn < 4; ++fn) wvA[fn] = *reinterpret_cast<const s16x8*>(wp + fn * 4096);

#define KV_STEP(KK, WREG)                                                           \
    {                                                                               \
        s16x8 a2[4];                                                                \
        _Pragma("unroll")                                                           \
        for (int fm = 0; fm < 4; ++fm)                                              \
            a2[fm] = *reinterpret_cast<const s16x8*>(tokbf + (fm * 16 + l15) * 264  \
                                                     + (KK) * 32 + quad * 8);       \
        _Pragma("unroll")                                                           \
        for (int fn = 0; fn < 4; ++fn)                                              \
            _Pragma("unroll")                                                       \
            for (int fm = 0; fm < 4; ++fm)                                          \
                kacc[fm][fn] = mfma16(a2[fm], (WREG)[fn], kacc[fm][fn]);            \
    }

    #pragma unroll 1
    for (int kc = 0; kc < 8; kc += 2) {
        #pragma unroll
        for (int fn = 0; fn < 4; ++fn)
            wvB[fn] = *reinterpret_cast<const s16x8*>(wp + fn * 4096 + (kc + 1) * 32);
        KV_STEP(kc, wvA)
        if (kc + 2 < 8) {
            #pragma unroll
            for (int fn = 0; fn < 4; ++fn)
                wvA[fn] = *reinterpret_cast<const s16x8*>(wp + fn * 4096 + (kc + 2) * 32);
        }
        KV_STEP(kc + 1, wvB)
    }
#undef KV_STEP

    #pragma unroll
    for (int fm = 0; fm < 4; ++fm)
        #pragma unroll
        for (int r = 0; r < 4; ++r) {
            int l = (ox * 16 + oyb * 4 + fm) * 16 + quad * 4 + r;
            #pragma unroll
            for (int fn = 0; fn < 4; ++fn) {
                int n = n2 + fn * 16 + l15;
                u16 v = f2bf(kacc[fm][fn][r]);
                if (n < 256) kbuf[((b << 12) + l) * 256 + n] = v;           // k[b][l][d]
                else         vT[((b * 256 + (n - 256)) << 12) + l] = v;     // vT[b][d][l]
            }
        }
}

// ============ kQ: init tpl; LN_t + q (iter 0); b = blk (XCD-pinned) ============
__global__ __launch_bounds__(256) void kQ(
    const float* __restrict__ tinit, float* __restrict__ tpl,
    const float* __restrict__ ln_t_g, const float* __restrict__ ln_t_b,
    const u16* __restrict__ WqP, u16* __restrict__ qbuf)
{
    __shared__ __align__(16) u16 mls[64 * 264];
    __shared__ float pls[64][4][2];
    __shared__ float stat[64][2];
    int b = blockIdx.x, tid = threadIdx.x;
    int m = tid >> 2, part = tid & 3;
    const float* tp = tinit + m * 256 + part * 64;
    float* tg = tpl + (b * 64 + m) * 256 + part * 64;
    float s = 0, q2 = 0;
    for (int i = 0; i < 64; ++i) {
        float v = tp[i];
        tg[i] = v;
        s += v; q2 += v * v;
    }
    pls[m][part][0] = s; pls[m][part][1] = q2;
    __syncthreads();
    if (tid < 64) {
        float ss = 0, qq = 0;
        #pragma unroll
        for (int p = 0; p < 4; ++p) { ss += pls[tid][p][0]; qq += pls[tid][p][1]; }
        float mu = ss * (1.f / 256.f);
        float var = fmaxf(qq * (1.f / 256.f) - mu * mu, 0.f);
        stat[tid][0] = mu; stat[tid][1] = rsqrtf(var + 1e-5f);
    }
    __syncthreads();
    {
        float mu = stat[m][0], rs = stat[m][1];
        for (int i = 0; i < 64; ++i) {
            int d = part * 64 + i;
            mls[m * 264 + d] = f2bf((tp[i] - mu) * rs * ln_t_g[d] + ln_t_b[d]);
        }
    }
    __syncthreads();
    int wid = tid >> 6, lane = tid & 63, quad = lane >> 4, l15 = lane & 15;
    f32x4 qa[4][4];
    #pragma unroll
    for (int i = 0; i < 4; ++i)
        #pragma unroll
        for (int j = 0; j < 4; ++j) qa[i][j] = ZERO4;
    #pragma unroll 1
    for (int kc = 0; kc < 8; ++kc) {
        s16x8 a[4];
        #pragma unroll
        for (int fm = 0; fm < 4; ++fm)
            a[fm] = *reinterpret_cast<const s16x8*>(mls + (fm * 16 + l15) * 264 + kc * 32 + quad * 8);
        #pragma unroll
        for (int fn = 0; fn < 4; ++fn) {
            s16x8 bv = *reinterpret_cast<const s16x8*>(WqP + (wid * 64 + fn * 16 + l15) * 256 + kc * 32 + quad * 8);
            #pragma unroll
            for (int fm = 0; fm < 4; ++fm)
                qa[fm][fn] = mfma16(a[fm], bv, qa[fm][fn]);
        }
    }
    #pragma unroll
    for (int fm = 0; fm < 4; ++fm)
        #pragma unroll
        for (int fn = 0; fn < 4; ++fn)
            #pragma unroll
            for (int r = 0; r < 4; ++r) {
                int mt = fm * 16 + quad * 4 + r;
                int d = wid * 64 + fn * 16 + l15;
                qbuf[(b * 64 + mt) * 256 + d] = f2bf(qa[fm][fn][r] * 0.0625f);
            }
}

// ============ kP: logits + softmax(N) -> P (bf16, attnT) + colsum partials ============
// grid 256; b = blk&7 (XCD-pinned); block 512 (8 waves); 128 l rows per block. NO atomics.
__global__ __launch_bounds__(512, 2) void kP(
    const u16* __restrict__ qbuf, const u16* __restrict__ kbuf,
    float* __restrict__ cs_part, u16* __restrict__ attnT)
{
    __shared__ __align__(16) u16 atile[64 * 136];     // [n][l_local] bf16, 17408 B
    __shared__ float colsh[8][64];
    int b = blockIdx.x & 7, ltg = blockIdx.x >> 3;    // XCD pin: b = blk%8
    int tid = threadIdx.x, wid = tid >> 6, lane = tid & 63;
    int quad = lane >> 4, l15 = lane & 15;
    const u16* qb = qbuf + b * 16384;
    int lrow = ltg * 128 + wid * 16;
    const u16* arow = kbuf + (size_t)((b << 12) + lrow + l15) * 256;
    f32x4 sa[4];
    #pragma unroll
    for (int fn = 0; fn < 4; ++fn) sa[fn] = ZERO4;
    #pragma unroll 2
    for (int kc = 0; kc < 8; ++kc) {
        s16x8 a = *reinterpret_cast<const s16x8*>(arow + kc * 32 + quad * 8);
        #pragma unroll
        for (int fn = 0; fn < 4; ++fn) {
            s16x8 bv = *reinterpret_cast<const s16x8*>(qb + (fn * 16 + l15) * 256 + kc * 32 + quad * 8);
            sa[fn] = mfma16(a, bv, sa[fn]);
        }
    }
    float colp[4] = {0.f, 0.f, 0.f, 0.f};
    #pragma unroll
    for (int r = 0; r < 4; ++r) {
        float mx = fmaxf(fmaxf(sa[0][r], sa[1][r]), fmaxf(sa[2][r], sa[3][r]));
        #pragma unroll
        for (int msk = 1; msk <= 8; msk <<= 1) mx = fmaxf(mx, __shfl_xor(mx, msk, 64));
        float e[4], sum = 0;
        #pragma unroll
        for (int fn = 0; fn < 4; ++fn) { e[fn] = __expf(sa[fn][r] - mx); sum += e[fn]; }
        #pragma unroll
        for (int msk = 1; msk <= 8; msk <<= 1) sum += __shfl_xor(sum, msk, 64);
        float inv = 1.f / sum;
        #pragma unroll
        for (int fn = 0; fn < 4; ++fn) {
            float p = e[fn] * inv + 1e-8f;
            colp[fn] += p;
            atile[(fn * 16 + l15) * 136 + wid * 16 + quad * 4 + r] = f2bf(p);
        }
    }
    #pragma unroll
    for (int fn = 0; fn < 4; ++fn) {
        float c = colp[fn];
        c += __shfl_xor(c, 16, 64);
        c += __shfl_xor(c, 32, 64);
        if (lane < 16) colsh[wid][fn * 16 + lane] = c;
    }
    __syncthreads();
    if (tid < 64) {
        float s = 0;
        #pragma unroll
        for (int w = 0; w < 8; ++w) s += colsh[w][tid];
        cs_part[((b << 5) + ltg) * 64 + tid] = s;
    }
    // ---- P tile out: attnT[b][n][l], coalesced 32 B/thread ----
    {
        int n = tid >> 3, lo = (tid & 7) * 16;
        const u16* src = atile + n * 136 + lo;
        u16* dst = attnT + (size_t)((b * 64 + n) << 12) + ltg * 128 + lo;
        *(int4*)(dst)     = *(const int4*)(src);
        *(int4*)(dst + 8) = *(const int4*)(src + 8);
    }
}

// ============ kPV: delta[b][n][d] = sum_l P[n][l] * vT[d][l]  (K=4096, no atomics) ============
// grid 128; b = blk&7 (XCD-pinned); block 512 (8 waves); wave w covers K-chunk w*512..+512
__global__ __launch_bounds__(512, 2) void kPV(
    const u16* __restrict__ attnT, const u16* __restrict__ vT, float* __restrict__ delta)
{
    __shared__ float pred[8][64][16];                 // 32768 B
    int b = blockIdx.x & 7, dt = blockIdx.x >> 3;     // XCD pin: b = blk%8
    int tid = threadIdx.x, wid = tid >> 6, lane = tid & 63;
    int quad = lane >> 4, l15 = lane & 15;
    const u16* prow = attnT + (size_t)((b * 64 + l15) << 12) + wid * 512 + quad * 8;
    const u16* vrow = vT + (size_t)((b * 256 + dt * 16 + l15) << 12) + wid * 512 + quad * 8;
    f32x4 acc[4];
    #pragma unroll
    for (int i = 0; i < 4; ++i) acc[i] = ZERO4;
    // A/B register prefetch one K-step ahead (5 loads feed 4 MFMAs; hide LLC/L2 latency)
    s16x8 aA[4], bA, aB[4], bB;
    bA = *reinterpret_cast<const s16x8*>(vrow);
    #pragma unroll
    for (int fm = 0; fm < 4; ++fm) aA[fm] = *reinterpret_cast<const s16x8*>(prow + (fm << 16));
    #pragma unroll 1
    for (int kc = 0; kc < 16; kc += 2) {
        bB = *reinterpret_cast<const s16x8*>(vrow + (kc + 1) * 32);
        #pragma unroll
        for (int fm = 0; fm < 4; ++fm)
            aB[fm] = *reinterpret_cast<const s16x8*>(prow + (fm << 16) + (kc + 1) * 32);
        #pragma unroll
        for (int fm = 0; fm < 4; ++fm) acc[fm] = mfma16(aA[fm], bA, acc[fm]);
        if (kc + 2 < 16) {
            bA = *reinterpret_cast<const s16x8*>(vrow + (kc + 2) * 32);
            #pragma unroll
            for (int fm = 0; fm < 4; ++fm)
                aA[fm] = *reinterpret_cast<const s16x8*>(prow + (fm << 16) + (kc + 2) * 32);
        }
        #pragma unroll
        for (int fm = 0; fm < 4; ++fm) acc[fm] = mfma16(aB[fm], bB, acc[fm]);
    }
    #pragma unroll
    for (int fm = 0; fm < 4; ++fm)
        #pragma unroll
        for (int r = 0; r < 4; ++r)
            pred[wid][fm * 16 + quad * 4 + r][l15] = acc[fm][r];
    __syncthreads();
    for (int i = tid; i < 1024; i += 512) {
        int n = i >> 4, d = i & 15;
        float s = 0;
        #pragma unroll
        for (int w = 0; w < 8; ++w) s += pred[w][n][d];
        delta[(size_t)(b * 64 + n) * 256 + dt * 16 + d] = s;
    }
}

// ============ kT: tpl += delta/colsum; LN_m; MLP; tpl += mlp; LN_t + q (next) ============
// grid 32; b = blk&7 (XCD-pinned); 16 templates per block
__global__ __launch_bounds__(256) void kT(
    float* __restrict__ tpl, const float* __restrict__ delta, const float* __restrict__ cs_part,
    float* __restrict__ colsum,
    const float* __restrict__ ln_m_g, const float* __restrict__ ln_m_b,
    const u16* __restrict__ W1T, const float* __restrict__ b1,
    const u16* __restrict__ W2T, const float* __restrict__ b2,
    const float* __restrict__ ln_t_g, const float* __restrict__ ln_t_b,
    const u16* __restrict__ WqP, u16* __restrict__ qbuf,
    int last, float* __restrict__ out0)
{
    __shared__ __align__(16) u16 mls[16 * 264];      // 8448
    __shared__ __align__(16) u16 hid[16 * 520];      // 16640
    __shared__ float pls[16][16][2];                 // 2048
    __shared__ float stat[16][2];
    __shared__ float lnr2[4][16][2];
    __shared__ float csh[16];
    int b = blockIdx.x & 7, mg = blockIdx.x >> 3;    // XCD pin: b = blk%8
    int m0 = mg * 16;
    int tid = threadIdx.x, wid = tid >> 6, lane = tid & 63;
    int quad = lane >> 4, l15 = lane & 15;
    // ---- phase 0: reduce colsum partials ----
    if (tid < 16) {
        float s = 0;
        #pragma unroll
        for (int g = 0; g < 32; ++g) s += cs_part[((b << 5) + g) * 64 + m0 + tid];
        csh[tid] = 1.f / s;
        if (last) colsum[b * 64 + m0 + tid] = s;
    }
    __syncthreads();
    // ---- phase 1: v = tpl + delta/colsum; LN_m -> mls; tpl = v ----
    {
        int ml = tid >> 4, part = tid & 15;
        float cinv = csh[ml];
        float* tg = tpl + (b * 64 + m0 + ml) * 256 + part * 16;
        const float* dg = delta + (b * 64 + m0 + ml) * 256 + part * 16;
        float vbuf[16];
        float s = 0, q2 = 0;
        #pragma unroll
        for (int i = 0; i < 16; ++i) {
            float v = tg[i] + dg[i] * cinv;
            vbuf[i] = v; s += v; q2 += v * v;
        }
        pls[ml][part][0] = s; pls[ml][part][1] = q2;
        __syncthreads();
        if (tid < 16) {
            float ss = 0, qq = 0;
            #pragma unroll
            for (int p = 0; p < 16; ++p) { ss += pls[tid][p][0]; qq += pls[tid][p][1]; }
            float mu = ss * (1.f / 256.f);
            float var = fmaxf(qq * (1.f / 256.f) - mu * mu, 0.f);
            stat[tid][0] = mu; stat[tid][1] = rsqrtf(var + 1e-5f);
        }
        __syncthreads();
        float mu = stat[ml][0], rs = stat[ml][1];
        #pragma unroll
        for (int i = 0; i < 16; ++i) {
            int d = part * 16 + i;
            tg[i] = vbuf[i];
            mls[ml * 264 + d] = f2bf((vbuf[i] - mu) * rs * ln_m_g[d] + ln_m_b[d]);
        }
    }
    __syncthreads();
    // ---- G1: hid = gelu(mls @ W1 + b1); wave -> 128 nh slice ----
    {
        f32x4 ha[8];
        #pragma unroll
        for (int j = 0; j < 8; ++j) ha[j] = ZERO4;
        #pragma unroll 1
        for (int kc = 0; kc < 8; ++kc) {
            s16x8 a = *reinterpret_cast<const s16x8*>(mls + l15 * 264 + kc * 32 + quad * 8);
            #pragma unroll
            for (int fn = 0; fn < 8; ++fn) {
                s16x8 bv = *reinterpret_cast<const s16x8*>(W1T + (wid * 128 + fn * 16 + l15) * 256 + kc * 32 + quad * 8);
                ha[fn] = mfma16(a, bv, ha[fn]);
            }
        }
        #pragma unroll
        for (int fn = 0; fn < 8; ++fn) {
            int nh = wid * 128 + fn * 16 + l15;
            float bb = b1[nh];
            #pragma unroll
            for (int r = 0; r < 4; ++r) {
                float v = ha[fn][r] + bb;
                v = 0.5f * v * (1.f + erff(v * 0.70710678118654752f));
                hid[(quad * 4 + r) * 520 + nh] = f2bf(v);
            }
        }
    }
    __syncthreads();
    // ---- G2: new = tpl + hid @ W2 + b2; LN_t -> mls; out0 on last ----
    {
        f32x4 oa[4];
        #pragma unroll
        for (int j = 0; j < 4; ++j) oa[j] = ZERO4;
        #pragma unroll 1
        for (int kc = 0; kc < 16; ++kc) {
            s16x8 a = *reinterpret_cast<const s16x8*>(hid + l15 * 520 + kc * 32 + quad * 8);
            #pragma unroll
            for (int fn = 0; fn < 4; ++fn) {
                s16x8 bv = *reinterpret_cast<const s16x8*>(W2T + (wid * 64 + fn * 16 + l15) * 512 + kc * 32 + quad * 8);
                oa[fn] = mfma16(a, bv, oa[fn]);
            }
        }
        #pragma unroll
        for (int fn = 0; fn < 4; ++fn) {
            int d = wid * 64 + fn * 16 + l15;
            float bb = b2[d];
            #pragma unroll
            for (int r = 0; r < 4; ++r) {
                int mm = quad * 4 + r;
                oa[fn][r] += bb + tpl[(b * 64 + m0 + mm) * 256 + d];
            }
        }
        // LN_t stats over the 16 new template rows
        #pragma unroll
        for (int r = 0; r < 4; ++r) {
            float s = oa[0][r] + oa[1][r] + oa[2][r] + oa[3][r];
            float q2 = oa[0][r] * oa[0][r] + oa[1][r] * oa[1][r]
                     + oa[2][r] * oa[2][r] + oa[3][r] * oa[3][r];
            #pragma unroll
            for (int msk = 1; msk <= 8; msk <<= 1) {
                s  += __shfl_xor(s, msk, 64);
                q2 += __shfl_xor(q2, msk, 64);
            }
            if (l15 == 0) {
                lnr2[wid][quad * 4 + r][0] = s;
                lnr2[wid][quad * 4 + r][1] = q2;
            }
        }
        __syncthreads();
        if (tid < 16) {
            float ss = 0, qq = 0;
            #pragma unroll
            for (int w = 0; w < 4; ++w) { ss += lnr2[w][tid][0]; qq += lnr2[w][tid][1]; }
            float mu = ss * (1.f / 256.f);
            float var = fmaxf(qq * (1.f / 256.f) - mu * mu, 0.f);
            stat[tid][0] = mu; stat[tid][1] = rsqrtf(var + 1e-5f);
        }
        __syncthreads();
        #pragma unroll
        for (int fn = 0; fn < 4; ++fn) {
            int d = wid * 64 + fn * 16 + l15;
            float gg = last ? 0.f : ln_t_g[d];
            float bt = last ? 0.f : ln_t_b[d];
            #pragma unroll
            for (int r = 0; r < 4; ++r) {
                int mm = quad * 4 + r;
                float v = oa[fn][r];
                tpl[(b * 64 + m0 + mm) * 256 + d] = v;
                if (last) {
                    out0[(b * 256 + d) * 64 + m0 + mm] = v;
                } else {
                    mls[mm * 264 + d] = f2bf((v - stat[mm][0]) * stat[mm][1] * gg + bt);
                }
            }
        }
    }
    if (!last) {
        __syncthreads();
        // ---- q-GEMM for next iteration ----
        f32x4 qa[4];
        #pragma unroll
        for (int j = 0; j < 4; ++j) qa[j] = ZERO4;
        #pragma unroll 1
        for (int kc = 0; kc < 8; ++kc) {
            s16x8 a = *reinterpret_cast<const s16x8*>(mls + l15 * 264 + kc * 32 + quad * 8);
            #pragma unroll
            for (int fn = 0; fn < 4; ++fn) {
                s16x8 bv = *reinterpret_cast<const s16x8*>(WqP + (wid * 64 + fn * 16 + l15) * 256 + kc * 32 + quad * 8);
                qa[fn] = mfma16(a, bv, qa[fn]);
            }
        }
        #pragma unroll
        for (int fn = 0; fn < 4; ++fn)
            #pragma unroll
            for (int r = 0; r < 4; ++r) {
                int mt = m0 + quad * 4 + r;
                int d = wid * 64 + fn * 16 + l15;
                qbuf[(b * 64 + mt) * 256 + d] = f2bf(qa[fn][r] * 0.0625f);
            }
    }
}

// ============ kE: attn_out = attnT / colsum; b = blk&7 (XCD-pinned) ============
__global__ void kE(const u16* __restrict__ attnT, const float* __restrict__ colsum,
                   float* __restrict__ out1)
{
    int blk = blockIdx.x;
    int b = blk & 7, r8 = blk >> 3;                  // XCD pin: b = blk%8
    int e = (b << 18) + (r8 << 10) + threadIdx.x * 4;
    int n = (e >> 12) & 63;
    float ci = 1.f / colsum[b * 64 + n];
    const u16* s = attnT + e;
    f32x4 o;
    o.x = bf2f(s[0]) * ci; o.y = bf2f(s[1]) * ci;
    o.z = bf2f(s[2]) * ci; o.w = bf2f(s[3]) * ci;
    *(f32x4*)(out1 + e) = o;
}

// ============ launch ============
extern "C" void kernel_launch(void* const* d_in, const int* in_sizes, int n_in,
                              void* d_out, int out_size, void* d_ws, size_t ws_size,
                              hipStream_t stream)
{
    const float* x       = (const float*)d_in[0];
    const float* tinit   = (const float*)d_in[1];
    const float* conv_w  = (const float*)d_in[2];
    const float* conv_b  = (const float*)d_in[3];
    const float* Wq      = (const float*)d_in[4];
    const float* Wk      = (const float*)d_in[5];
    const float* Wv      = (const float*)d_in[6];
    const float* ln_in_g = (const float*)d_in[7];
    const float* ln_in_b = (const float*)d_in[8];
    const float* ln_t_g  = (const float*)d_in[9];
    const float* ln_t_b  = (const float*)d_in[10];
    const float* ln_m_g  = (const float*)d_in[11];
    const float* ln_m_b  = (const float*)d_in[12];
    const float* W1      = (const float*)d_in[13];
    const float* b1      = (const float*)d_in[14];
    const float* W2      = (const float*)d_in[15];
    const float* b2      = (const float*)d_in[16];

    char* ws = (char*)d_ws;
    u16* Bp       = (u16*)(ws + 0);          // 2,359,296
    u16* WkvP     = (u16*)(ws + 2359296);    //   262,144
    u16* WqP      = (u16*)(ws + 2621440);    //   131,072
    u16* W1T      = (u16*)(ws + 2752512);    //   262,144
    u16* W2T      = (u16*)(ws + 3014656);    //   262,144
    u16* kbuf     = (u16*)(ws + 3276800);    // 16,777,216
    u16* vT       = (u16*)(ws + 20054016);   // 16,777,216
    u16* qbuf     = (u16*)(ws + 36831232);   //   262,144
    u16* attnT    = (u16*)(ws + 37093376);   // 4,194,304  (P every iter; attn out last)
    float* colsum = (float*)(ws + 41287680); //     2,048
    float* tpl    = (float*)(ws + 41289728); //   524,288
    float* delta  = (float*)(ws + 41814016); //   524,288
    float* cs_part= (float*)(ws + 42338304); //    65,536   (total ~42.4 MB)

    float* out0 = (float*)d_out;      // templates_out (8,256,64)
    float* out1 = out0 + 131072;      // attn_out (8,64,16,16,16)

    prepack_kernel<<<2944, 256, 0, stream>>>(conv_w, Wk, Wv, Wq, W1, W2, Bp, WkvP, WqP, W1T, W2T);
    conv_fused<<<512, 512, 0, stream>>>(x, Bp, conv_b, ln_in_g, ln_in_b, WkvP, kbuf, vT);
    kQ<<<8, 256, 0, stream>>>(tinit, tpl, ln_t_g, ln_t_b, WqP, qbuf);
    for (int it = 0; it < 6; ++it) {
        int last = (it == 5) ? 1 : 0;
        kP<<<256, 512, 0, stream>>>(qbuf, kbuf, cs_part, attnT);
        kPV<<<128, 512, 0, stream>>>(attnT, vT, delta);
        kT<<<32, 256, 0, stream>>>(tpl, delta, cs_part, colsum, ln_m_g, ln_m_b, W1T, b1, W2T, b2,
                                   ln_t_g, ln_t_b, WqP, qbuf, last, out0);
    }
    kE<<<2048, 256, 0, stream>>>(attnT, colsum, out1);
}

// Round 5
// 749.071 us; speedup vs baseline: 3.7931x; 1.0764x over previous
//
#include <hip/hip_runtime.h>

typedef unsigned short u16;
typedef short s16x8 __attribute__((ext_vector_type(8)));
typedef float f32x4 __attribute__((ext_vector_type(4)));
typedef float f32x4u __attribute__((ext_vector_type(4), aligned(4)));
typedef unsigned short us4 __attribute__((ext_vector_type(4)));   // 8 B

__device__ __forceinline__ float bf2f(u16 v) {
    return __uint_as_float(((unsigned int)v) << 16);
}
__device__ __forceinline__ u16 f2bf(float f) {
    unsigned int u = __float_as_uint(f);
    u = u + 0x7FFFu + ((u >> 16) & 1u);
    return (u16)(u >> 16);
}
__device__ __forceinline__ f32x4 mfma16(s16x8 a, s16x8 b, f32x4 c) {
    return __builtin_amdgcn_mfma_f32_16x16x32_bf16(a, b, c, 0, 0, 0);
}
#define ZERO4 f32x4{0.f, 0.f, 0.f, 0.f}

// ============ prepack: f32 weights -> bf16 MFMA B-fragment layouts ============
__global__ void prepack_kernel(const float* __restrict__ conv_w, const float* __restrict__ Wk,
                               const float* __restrict__ Wv, const float* __restrict__ Wq,
                               const float* __restrict__ W1, const float* __restrict__ W2,
                               u16* __restrict__ Bp, u16* __restrict__ WkvP, u16* __restrict__ WqP,
                               u16* __restrict__ W1T, u16* __restrict__ W2T)
{
    int idx = blockIdx.x * 256 + threadIdx.x;
    if (idx < 294912) {                       // 256 n * 1152 groups
        int n = idx / 1152, g = idx - n * 1152;
        int ic = g / 9, r = g - ic * 9;
        const float* s = conv_w + n * 3456 + ic * 27 + r * 3;
        u16* d = Bp + n * 4608 + g * 4;
        d[0] = f2bf(s[0]); d[1] = f2bf(s[1]); d[2] = f2bf(s[2]); d[3] = 0;
    } else if (idx < 425984) {                // WkvP 512*256
        int i = idx - 294912;
        int n = i >> 8, c = i & 255;
        WkvP[i] = f2bf((n < 256) ? Wk[c * 256 + n] : Wv[c * 256 + (n - 256)]);
    } else if (idx < 491520) {                // WqP 256*256
        int i = idx - 425984;
        int n = i >> 8, c = i & 255;
        WqP[i] = f2bf(Wq[c * 256 + n]);
    } else if (idx < 622592) {                // W1T 512*256
        int i = idx - 491520;
        int h = i >> 8, c = i & 255;
        W1T[i] = f2bf(W1[c * 512 + h]);
    } else if (idx < 753664) {                // W2T 256*512
        int i = idx - 622592;
        int dd = i >> 9, h = i & 511;
        W2T[i] = f2bf(W2[h * 256 + dd]);
    }
}

// ============ fused conv3d(s2)+bias+ReLU+LN_in + k/v GEMM ============
// grid 512; b = blk&7 (XCD-pinned); block 512 (8 waves); M-tile 64 tokens
__global__ __launch_bounds__(512, 4) void conv_fused(
    const float* __restrict__ x, const u16* __restrict__ Bp, const float* __restrict__ conv_b,
    const float* __restrict__ ln_g, const float* __restrict__ ln_b, const u16* __restrict__ WkvP,
    u16* __restrict__ kbuf, u16* __restrict__ vT)
{
    __shared__ __align__(16) char smem[38400];
    u16* slab   = (u16*)smem;                 // [432 rows][36 iz] u16 = 31104 B
    u16* tokbf  = (u16*)smem;                 // alias: [64 m][264 c] = 33792 B
    float* lnred  = (float*)(smem + 33792);   // [8 w][64 m][2] = 4096
    float* lnstat = (float*)(smem + 37888);   // [64 m][2] = 512

    int blk = blockIdx.x;
    int b = blk & 7, ox = (blk >> 5) & 15, oyb = (blk >> 3) & 3;   // XCD pin: b = blk%8
    int tid = threadIdx.x, wid = tid >> 6, lane = tid & 63;
    int quad = lane >> 4, l15 = lane & 15;
    int nbase = wid * 32;                     // conv n-slice: 32 channels/wave

    f32x4 acc[4][2];
    #pragma unroll
    for (int i = 0; i < 4; ++i)
        #pragma unroll
        for (int j = 0; j < 2; ++j) acc[i][j] = ZERO4;

    const u16* bprow0 = Bp + (nbase + l15) * 4608 + quad * 8;
    const u16* bprow1 = bprow0 + 16 * 4608;

    for (int icc = 0; icc < 8; ++icc) {
        __syncthreads();
        // ---- staging: 432 rows x 9 float4-slots = 3888 slots, 8/thread ----
        {
            f32x4u tv[8];
            int so8[8];
            #pragma unroll
            for (int u = 0; u < 8; ++u) {
                int s = tid + u * 512;
                tv[u] = f32x4u{0.f, 0.f, 0.f, 0.f};
                so8[u] = -1;
                if (s < 3888) {
                    int row = s / 9;
                    int c = s - row * 9;
                    int icl = row / 27;
                    int rr = row - icl * 27;
                    int ixl = rr / 9;
                    int iyl = rr - ixl * 9;
                    const float* xr = x + ((size_t)((b * 128 + icc * 16 + icl) * 33)
                                           + (2 * ox + ixl)) * 1089 + (8 * oyb + iyl) * 33;
                    if (c < 8) tv[u] = *(const f32x4u*)(xr + c * 4);
                    else       tv[u].x = xr[32];          // iz 32; 33..35 stay 0
                    so8[u] = row * 36 + c * 4;
                }
            }
            #pragma unroll
            for (int u = 0; u < 8; ++u) {
                if (so8[u] >= 0) {
                    us4 w;
                    w.x = f2bf(tv[u].x); w.y = f2bf(tv[u].y);
                    w.z = f2bf(tv[u].z); w.w = f2bf(tv[u].w);
                    *(us4*)(slab + so8[u]) = w;
                }
            }
        }
        __syncthreads();

        const u16* bk0 = bprow0 + icc * 576;
        const u16* bk1 = bprow1 + icc * 576;
        s16x8 bbA[2], bbB[2];
        bbA[0] = *reinterpret_cast<const s16x8*>(bk0);
        bbA[1] = *reinterpret_cast<const s16x8*>(bk1);

#define CONV_STEP(CC, BREG)                                                     \
        {                                                                       \
            int g = (CC) * 8 + quad * 2;                                        \
            int i0 = g / 9, r9 = g - i0 * 9;                                    \
            int kx = r9 / 3, ky = r9 - kx * 3;                                  \
            int base0 = (i0 * 27 + kx * 9 + ky) * 36 + 2 * l15;                 \
            g += 1;                                                             \
            i0 = g / 9; r9 = g - i0 * 9; kx = r9 / 3; ky = r9 - kx * 3;         \
            int base1 = (i0 * 27 + kx * 9 + ky) * 36 + 2 * l15;                 \
            _Pragma("unroll")                                                   \
            for (int fm = 0; fm < 4; ++fm) {                                    \
                union { s16x8 v; ushort2 h[4]; } af;                            \
                const u16* sp0 = slab + base0 + fm * 72;                        \
                const u16* sp1 = slab + base1 + fm * 72;                        \
                af.h[0] = *(const ushort2*)(sp0);                               \
                af.h[1] = *(const ushort2*)(sp0 + 2);                           \
                af.h[2] = *(const ushort2*)(sp1);                               \
                af.h[3] = *(const ushort2*)(sp1 + 2);                           \
                acc[fm][0] = mfma16(af.v, (BREG)[0], acc[fm][0]);               \
                acc[fm][1] = mfma16(af.v, (BREG)[1], acc[fm][1]);               \
            }                                                                   \
        }

        #pragma unroll 1
        for (int c8 = 0; c8 < 18; c8 += 2) {
            bbB[0] = *reinterpret_cast<const s16x8*>(bk0 + (c8 + 1) * 32);
            bbB[1] = *reinterpret_cast<const s16x8*>(bk1 + (c8 + 1) * 32);
            CONV_STEP(c8, bbA)
            if (c8 + 2 < 18) {
                bbA[0] = *reinterpret_cast<const s16x8*>(bk0 + (c8 + 2) * 32);
                bbA[1] = *reinterpret_cast<const s16x8*>(bk1 + (c8 + 2) * 32);
            }
            CONV_STEP(c8 + 1, bbB)
        }
#undef CONV_STEP
    }
    // ---- bias + relu ----
    #pragma unroll
    for (int fn = 0; fn < 2; ++fn) {
        float bias = conv_b[nbase + fn * 16 + l15];
        #pragma unroll
        for (int fm = 0; fm < 4; ++fm)
            #pragma unroll
            for (int r = 0; r < 4; ++r)
                acc[fm][fn][r] = fmaxf(acc[fm][fn][r] + bias, 0.f);
    }
    // ---- LN_in ----
    #pragma unroll
    for (int fm = 0; fm < 4; ++fm) {
        #pragma unroll
        for (int r = 0; r < 4; ++r) {
            float s = acc[fm][0][r] + acc[fm][1][r];
            float q2 = acc[fm][0][r] * acc[fm][0][r] + acc[fm][1][r] * acc[fm][1][r];
            #pragma unroll
            for (int msk = 1; msk <= 8; msk <<= 1) {
                s  += __shfl_xor(s, msk, 64);
                q2 += __shfl_xor(q2, msk, 64);
            }
            if (l15 == 0) {
                int mm = fm * 16 + quad * 4 + r;
                lnred[(wid * 64 + mm) * 2 + 0] = s;
                lnred[(wid * 64 + mm) * 2 + 1] = q2;
            }
        }
    }
    __syncthreads();
    if (tid < 64) {
        float s = 0, q2 = 0;
        #pragma unroll
        for (int w = 0; w < 8; ++w) { s += lnred[(w * 64 + tid) * 2]; q2 += lnred[(w * 64 + tid) * 2 + 1]; }
        float mu = s * (1.f / 256.f);
        float var = fmaxf(q2 * (1.f / 256.f) - mu * mu, 0.f);
        lnstat[tid * 2]     = mu;
        lnstat[tid * 2 + 1] = rsqrtf(var + 1e-5f);
    }
    __syncthreads();
    {
        float gam[2], bet[2];
        #pragma unroll
        for (int fn = 0; fn < 2; ++fn) {
            int n = nbase + fn * 16 + l15;
            gam[fn] = ln_g[n]; bet[fn] = ln_b[n];
        }
        #pragma unroll
        for (int fm = 0; fm < 4; ++fm)
            #pragma unroll
            for (int r = 0; r < 4; ++r) {
                int mm = fm * 16 + quad * 4 + r;
                float mu = lnstat[mm * 2], rs = lnstat[mm * 2 + 1];
                #pragma unroll
                for (int fn = 0; fn < 2; ++fn) {
                    int n = nbase + fn * 16 + l15;
                    tokbf[mm * 264 + n] = f2bf((acc[fm][fn][r] - mu) * rs * gam[fn] + bet[fn]);
                }
            }
    }
    __syncthreads();
    // ---- k/v GEMM: [64 m]x[512 n], K=256; each wave owns 64 n for all m ----
    f32x4 kacc[4][4];
    #pragma unroll
    for (int i = 0; i < 4; ++i)
        #pragma unroll
        for (int j = 0; j < 4; ++j) kacc[i][j] = ZERO4;
    int n2 = wid * 64;
    const u16* wp = WkvP + (n2 + l15) * 256 + quad * 8;
    s16x8 wvA[4], wvB[4];
    #pragma unroll
    for (int fn = 0; fn < 4; ++fn) wvA[fn] = *reinterpret_cast<const s16x8*>(wp + fn * 4096);

#define KV_STEP(KK, WREG)                                                           \
    {                                                                               \
        s16x8 a2[4];                                                                \
        _Pragma("unroll")                                                           \
        for (int fm = 0; fm < 4; ++fm)                                              \
            a2[fm] = *reinterpret_cast<const s16x8*>(tokbf + (fm * 16 + l15) * 264  \
                                                     + (KK) * 32 + quad * 8);       \
        _Pragma("unroll")                                                           \
        for (int fn = 0; fn < 4; ++fn)                                              \
            _Pragma("unroll")                                                       \
            for (int fm = 0; fm < 4; ++fm)                                          \
                kacc[fm][fn] = mfma16(a2[fm], (WREG)[fn], kacc[fm][fn]);            \
    }

    #pragma unroll 1
    for (int kc = 0; kc < 8; kc += 2) {
        #pragma unroll
        for (int fn = 0; fn < 4; ++fn)
            wvB[fn] = *reinterpret_cast<const s16x8*>(wp + fn * 4096 + (kc + 1) * 32);
        KV_STEP(kc, wvA)
        if (kc + 2 < 8) {
            #pragma unroll
            for (int fn = 0; fn < 4; ++fn)
                wvA[fn] = *reinterpret_cast<const s16x8*>(wp + fn * 4096 + (kc + 2) * 32);
        }
        KV_STEP(kc + 1, wvB)
    }
#undef KV_STEP

    #pragma unroll
    for (int fm = 0; fm < 4; ++fm)
        #pragma unroll
        for (int r = 0; r < 4; ++r) {
            int l = (ox * 16 + oyb * 4 + fm) * 16 + quad * 4 + r;
            #pragma unroll
            for (int fn = 0; fn < 4; ++fn) {
                int n = n2 + fn * 16 + l15;
                u16 v = f2bf(kacc[fm][fn][r]);
                if (n < 256) kbuf[((b << 12) + l) * 256 + n] = v;           // k[b][l][d]
                else         vT[((b * 256 + (n - 256)) << 12) + l] = v;     // vT[b][d][l]
            }
        }
}

// ============ kQ: init tpl; LN_t + q (iter 0); zero delta ============
__global__ __launch_bounds__(256) void kQ(
    const float* __restrict__ tinit, float* __restrict__ tpl,
    const float* __restrict__ ln_t_g, const float* __restrict__ ln_t_b,
    const u16* __restrict__ WqP, u16* __restrict__ qbuf, float* __restrict__ delta)
{
    __shared__ __align__(16) u16 mls[64 * 264];
    __shared__ float pls[64][4][2];
    __shared__ float stat[64][2];
    int b = blockIdx.x, tid = threadIdx.x;
    int m = tid >> 2, part = tid & 3;
    const float* tp = tinit + m * 256 + part * 64;
    float* tg = tpl + (b * 64 + m) * 256 + part * 64;
    float s = 0, q2 = 0;
    for (int i = 0; i < 64; ++i) {
        float v = tp[i];
        tg[i] = v;
        s += v; q2 += v * v;
    }
    pls[m][part][0] = s; pls[m][part][1] = q2;
    __syncthreads();
    if (tid < 64) {
        float ss = 0, qq = 0;
        #pragma unroll
        for (int p = 0; p < 4; ++p) { ss += pls[tid][p][0]; qq += pls[tid][p][1]; }
        float mu = ss * (1.f / 256.f);
        float var = fmaxf(qq * (1.f / 256.f) - mu * mu, 0.f);
        stat[tid][0] = mu; stat[tid][1] = rsqrtf(var + 1e-5f);
    }
    __syncthreads();
    {
        float mu = stat[m][0], rs = stat[m][1];
        for (int i = 0; i < 64; ++i) {
            int d = part * 64 + i;
            mls[m * 264 + d] = f2bf((tp[i] - mu) * rs * ln_t_g[d] + ln_t_b[d]);
        }
    }
    __syncthreads();
    int wid = tid >> 6, lane = tid & 63, quad = lane >> 4, l15 = lane & 15;
    f32x4 qa[4][4];
    #pragma unroll
    for (int i = 0; i < 4; ++i)
        #pragma unroll
        for (int j = 0; j < 4; ++j) qa[i][j] = ZERO4;
    #pragma unroll 1
    for (int kc = 0; kc < 8; ++kc) {
        s16x8 a[4];
        #pragma unroll
        for (int fm = 0; fm < 4; ++fm)
            a[fm] = *reinterpret_cast<const s16x8*>(mls + (fm * 16 + l15) * 264 + kc * 32 + quad * 8);
        #pragma unroll
        for (int fn = 0; fn < 4; ++fn) {
            s16x8 bv = *reinterpret_cast<const s16x8*>(WqP + (wid * 64 + fn * 16 + l15) * 256 + kc * 32 + quad * 8);
            #pragma unroll
            for (int fm = 0; fm < 4; ++fm)
                qa[fm][fn] = mfma16(a[fm], bv, qa[fm][fn]);
        }
    }
    #pragma unroll
    for (int fm = 0; fm < 4; ++fm)
        #pragma unroll
        for (int fn = 0; fn < 4; ++fn)
            #pragma unroll
            for (int r = 0; r < 4; ++r) {
                int mt = fm * 16 + quad * 4 + r;
                int d = wid * 64 + fn * 16 + l15;
                qbuf[(b * 64 + mt) * 256 + d] = f2bf(qa[fm][fn][r] * 0.0625f);
            }
    // zero delta[b] for iter-0 atomics
    f32x4* dz = (f32x4*)(delta + b * 16384);
    for (int i = tid; i < 4096; i += 256) dz[i] = ZERO4;
}

// ============ kA: fused logits+softmax+PV; grid 256; b = blk&7 (XCD-pinned) ============
// Phase A: S = k@q^T (128 l x 64 n), softmax over n -> P in LDS + colsum partials.
// Phase B: delta[n][d] += P[n][l-chunk] @ vT[d][l-chunk] via f32 atomics (K=128).
// attnT written only on last iter (kE input). qbuf staged in LDS (8x fewer gl reads).
__global__ __launch_bounds__(512, 2) void kA(
    const u16* __restrict__ qbuf, const u16* __restrict__ kbuf, const u16* __restrict__ vT,
    float* __restrict__ cs_part, float* __restrict__ delta, int last, u16* __restrict__ attnT)
{
    __shared__ __align__(16) u16 qls[64 * 264];       // 33792 B (pad 8: 2-way bank alias, free)
    __shared__ __align__(16) u16 atile[64 * 136];     // 17408 B [n][l_local]
    __shared__ float colsh[8][64];                    // 2048 B
    int b = blockIdx.x & 7, ltg = blockIdx.x >> 3;    // XCD pin: b = blk%8
    int tid = threadIdx.x, wid = tid >> 6, lane = tid & 63;
    int quad = lane >> 4, l15 = lane & 15;

    // ---- stage q[b] (32 KB) into LDS ----
    {
        int r = tid >> 3, c = (tid & 7) * 32;
        const u16* src = qbuf + b * 16384 + r * 256 + c;
        u16* dst = qls + r * 264 + c;
        #pragma unroll
        for (int j = 0; j < 4; ++j)
            *(int4*)(dst + j * 8) = *(const int4*)(src + j * 8);
    }
    // ---- issue all k-row loads up-front (overlap with staging) ----
    int lrow = ltg * 128 + wid * 16;
    const u16* arow = kbuf + (size_t)((b << 12) + lrow + l15) * 256;
    s16x8 av[8];
    #pragma unroll
    for (int kc = 0; kc < 8; ++kc)
        av[kc] = *reinterpret_cast<const s16x8*>(arow + kc * 32 + quad * 8);
    __syncthreads();
    // ---- Phase A: QK^T + softmax(N) ----
    f32x4 sa[4];
    #pragma unroll
    for (int fn = 0; fn < 4; ++fn) sa[fn] = ZERO4;
    #pragma unroll
    for (int kc = 0; kc < 8; ++kc) {
        #pragma unroll
        for (int fn = 0; fn < 4; ++fn) {
            s16x8 bv = *reinterpret_cast<const s16x8*>(qls + (fn * 16 + l15) * 264 + kc * 32 + quad * 8);
            sa[fn] = mfma16(av[kc], bv, sa[fn]);
        }
    }
    float colp[4] = {0.f, 0.f, 0.f, 0.f};
    #pragma unroll
    for (int r = 0; r < 4; ++r) {
        float mx = fmaxf(fmaxf(sa[0][r], sa[1][r]), fmaxf(sa[2][r], sa[3][r]));
        #pragma unroll
        for (int msk = 1; msk <= 8; msk <<= 1) mx = fmaxf(mx, __shfl_xor(mx, msk, 64));
        float e[4], sum = 0;
        #pragma unroll
        for (int fn = 0; fn < 4; ++fn) { e[fn] = __expf(sa[fn][r] - mx); sum += e[fn]; }
        #pragma unroll
        for (int msk = 1; msk <= 8; msk <<= 1) sum += __shfl_xor(sum, msk, 64);
        float inv = 1.f / sum;
        #pragma unroll
        for (int fn = 0; fn < 4; ++fn) {
            float p = e[fn] * inv + 1e-8f;
            colp[fn] += p;
            atile[(fn * 16 + l15) * 136 + wid * 16 + quad * 4 + r] = f2bf(p);
        }
    }
    #pragma unroll
    for (int fn = 0; fn < 4; ++fn) {
        float c = colp[fn];
        c += __shfl_xor(c, 16, 64);
        c += __shfl_xor(c, 32, 64);
        if (lane < 16) colsh[wid][fn * 16 + lane] = c;
    }
    __syncthreads();
    if (tid < 64) {
        float s = 0;
        #pragma unroll
        for (int w = 0; w < 8; ++w) s += colsh[w][tid];
        cs_part[((b << 5) + ltg) * 64 + tid] = s;
    }
    // ---- Phase B: PV, K = this block's 128 l; atomics into delta ----
    {
        const u16* vrow = vT + ((size_t)(b * 256 + wid * 32 + l15) << 12) + ltg * 128 + quad * 8;
        s16x8 bv2[2][4];
        #pragma unroll
        for (int fn = 0; fn < 2; ++fn)
            #pragma unroll
            for (int kc = 0; kc < 4; ++kc)
                bv2[fn][kc] = *reinterpret_cast<const s16x8*>(vrow + (fn << 16) + kc * 32);
        f32x4 pacc[4][2];
        #pragma unroll
        for (int i = 0; i < 4; ++i)
            #pragma unroll
            for (int j = 0; j < 2; ++j) pacc[i][j] = ZERO4;
        #pragma unroll
        for (int kc = 0; kc < 4; ++kc) {
            #pragma unroll
            for (int fm = 0; fm < 4; ++fm) {
                s16x8 a = *reinterpret_cast<const s16x8*>(atile + (fm * 16 + l15) * 136 + kc * 32 + quad * 8);
                #pragma unroll
                for (int fn = 0; fn < 2; ++fn)
                    pacc[fm][fn] = mfma16(a, bv2[fn][kc], pacc[fm][fn]);
            }
        }
        #pragma unroll
        for (int fm = 0; fm < 4; ++fm)
            #pragma unroll
            for (int fn = 0; fn < 2; ++fn)
                #pragma unroll
                for (int r = 0; r < 4; ++r) {
                    int n = fm * 16 + quad * 4 + r;
                    int d = wid * 32 + fn * 16 + l15;
                    atomicAdd(&delta[(size_t)(b * 64 + n) * 256 + d], pacc[fm][fn][r]);
                }
    }
    // ---- Phase C: P tile -> attnT on last iter only ----
    if (last) {
        int n = tid >> 3, lo = (tid & 7) * 16;
        const u16* src = atile + n * 136 + lo;
        u16* dst = attnT + (size_t)((b * 64 + n) << 12) + ltg * 128 + lo;
        *(int4*)(dst)     = *(const int4*)(src);
        *(int4*)(dst + 8) = *(const int4*)(src + 8);
    }
}

// ============ kT: tpl += delta/colsum (then zero delta); LN_m; MLP; LN_t + q ============
// grid 32; b = blk&7 (XCD-pinned); 16 templates per block
__global__ __launch_bounds__(256) void kT(
    float* __restrict__ tpl, float* __restrict__ delta, const float* __restrict__ cs_part,
    float* __restrict__ colsum,
    const float* __restrict__ ln_m_g, const float* __restrict__ ln_m_b,
    const u16* __restrict__ W1T, const float* __restrict__ b1,
    const u16* __restrict__ W2T, const float* __restrict__ b2,
    const float* __restrict__ ln_t_g, const float* __restrict__ ln_t_b,
    const u16* __restrict__ WqP, u16* __restrict__ qbuf,
    int last, float* __restrict__ out0)
{
    __shared__ __align__(16) u16 mls[16 * 264];      // 8448
    __shared__ __align__(16) u16 hid[16 * 520];      // 16640
    __shared__ float pls[16][16][2];                 // 2048
    __shared__ float stat[16][2];
    __shared__ float lnr2[4][16][2];
    __shared__ float csh[16];
    int b = blockIdx.x & 7, mg = blockIdx.x >> 3;    // XCD pin: b = blk%8
    int m0 = mg * 16;
    int tid = threadIdx.x, wid = tid >> 6, lane = tid & 63;
    int quad = lane >> 4, l15 = lane & 15;
    // ---- phase 0: reduce colsum partials ----
    if (tid < 16) {
        float s = 0;
        #pragma unroll
        for (int g = 0; g < 32; ++g) s += cs_part[((b << 5) + g) * 64 + m0 + tid];
        csh[tid] = 1.f / s;
        if (last) colsum[b * 64 + m0 + tid] = s;
    }
    __syncthreads();
    // ---- phase 1: v = tpl + delta/colsum; zero delta; LN_m -> mls; tpl = v ----
    {
        int ml = tid >> 4, part = tid & 15;
        float cinv = csh[ml];
        float* tg = tpl + (b * 64 + m0 + ml) * 256 + part * 16;
        float* dg = delta + (size_t)(b * 64 + m0 + ml) * 256 + part * 16;
        float vbuf[16];
        float s = 0, q2 = 0;
        #pragma unroll
        for (int i = 0; i < 16; ++i) {
            float v = tg[i] + dg[i] * cinv;
            vbuf[i] = v; s += v; q2 += v * v;
        }
        if (!last) {
            f32x4* dz = (f32x4*)dg;
            #pragma unroll
            for (int i = 0; i < 4; ++i) dz[i] = ZERO4;
        }
        pls[ml][part][0] = s; pls[ml][part][1] = q2;
        __syncthreads();
        if (tid < 16) {
            float ss = 0, qq = 0;
            #pragma unroll
            for (int p = 0; p < 16; ++p) { ss += pls[tid][p][0]; qq += pls[tid][p][1]; }
            float mu = ss * (1.f / 256.f);
            float var = fmaxf(qq * (1.f / 256.f) - mu * mu, 0.f);
            stat[tid][0] = mu; stat[tid][1] = rsqrtf(var + 1e-5f);
        }
        __syncthreads();
        float mu = stat[ml][0], rs = stat[ml][1];
        #pragma unroll
        for (int i = 0; i < 16; ++i) {
            int d = part * 16 + i;
            tg[i] = vbuf[i];
            mls[ml * 264 + d] = f2bf((vbuf[i] - mu) * rs * ln_m_g[d] + ln_m_b[d]);
        }
    }
    __syncthreads();
    // ---- G1: hid = gelu(mls @ W1 + b1); wave -> 128 nh slice ----
    {
        f32x4 ha[8];
        #pragma unroll
        for (int j = 0; j < 8; ++j) ha[j] = ZERO4;
        #pragma unroll 1
        for (int kc = 0; kc < 8; ++kc) {
            s16x8 a = *reinterpret_cast<const s16x8*>(mls + l15 * 264 + kc * 32 + quad * 8);
            #pragma unroll
            for (int fn = 0; fn < 8; ++fn) {
                s16x8 bv = *reinterpret_cast<const s16x8*>(W1T + (wid * 128 + fn * 16 + l15) * 256 + kc * 32 + quad * 8);
                ha[fn] = mfma16(a, bv, ha[fn]);
            }
        }
        #pragma unroll
        for (int fn = 0; fn < 8; ++fn) {
            int nh = wid * 128 + fn * 16 + l15;
            float bb = b1[nh];
            #pragma unroll
            for (int r = 0; r < 4; ++r) {
                float v = ha[fn][r] + bb;
                v = 0.5f * v * (1.f + erff(v * 0.70710678118654752f));
                hid[(quad * 4 + r) * 520 + nh] = f2bf(v);
            }
        }
    }
    __syncthreads();
    // ---- G2: new = tpl + hid @ W2 + b2; LN_t -> mls; out0 on last ----
    {
        f32x4 oa[4];
        #pragma unroll
        for (int j = 0; j < 4; ++j) oa[j] = ZERO4;
        #pragma unroll 1
        for (int kc = 0; kc < 16; ++kc) {
            s16x8 a = *reinterpret_cast<const s16x8*>(hid + l15 * 520 + kc * 32 + quad * 8);
            #pragma unroll
            for (int fn = 0; fn < 4; ++fn) {
                s16x8 bv = *reinterpret_cast<const s16x8*>(W2T + (wid * 64 + fn * 16 + l15) * 512 + kc * 32 + quad * 8);
                oa[fn] = mfma16(a, bv, oa[fn]);
            }
        }
        #pragma unroll
        for (int fn = 0; fn < 4; ++fn) {
            int d = wid * 64 + fn * 16 + l15;
            float bb = b2[d];
            #pragma unroll
            for (int r = 0; r < 4; ++r) {
                int mm = quad * 4 + r;
                oa[fn][r] += bb + tpl[(b * 64 + m0 + mm) * 256 + d];
            }
        }
        // LN_t stats over the 16 new template rows
        #pragma unroll
        for (int r = 0; r < 4; ++r) {
            float s = oa[0][r] + oa[1][r] + oa[2][r] + oa[3][r];
            float q2 = oa[0][r] * oa[0][r] + oa[1][r] * oa[1][r]
                     + oa[2][r] * oa[2][r] + oa[3][r] * oa[3][r];
            #pragma unroll
            for (int msk = 1; msk <= 8; msk <<= 1) {
                s  += __shfl_xor(s, msk, 64);
                q2 += __shfl_xor(q2, msk, 64);
            }
            if (l15 == 0) {
                lnr2[wid][quad * 4 + r][0] = s;
                lnr2[wid][quad * 4 + r][1] = q2;
            }
        }
        __syncthreads();
        if (tid < 16) {
            float ss = 0, qq = 0;
            #pragma unroll
            for (int w = 0; w < 4; ++w) { ss += lnr2[w][tid][0]; qq += lnr2[w][tid][1]; }
            float mu = ss * (1.f / 256.f);
            float var = fmaxf(qq * (1.f / 256.f) - mu * mu, 0.f);
            stat[tid][0] = mu; stat[tid][1] = rsqrtf(var + 1e-5f);
        }
        __syncthreads();
        #pragma unroll
        for (int fn = 0; fn < 4; ++fn) {
            int d = wid * 64 + fn * 16 + l15;
            float gg = last ? 0.f : ln_t_g[d];
            float bt = last ? 0.f : ln_t_b[d];
            #pragma unroll
            for (int r = 0; r < 4; ++r) {
                int mm = quad * 4 + r;
                float v = oa[fn][r];
                tpl[(b * 64 + m0 + mm) * 256 + d] = v;
                if (last) {
                    out0[(b * 256 + d) * 64 + m0 + mm] = v;
                } else {
                    mls[mm * 264 + d] = f2bf((v - stat[mm][0]) * stat[mm][1] * gg + bt);
                }
            }
        }
    }
    if (!last) {
        __syncthreads();
        // ---- q-GEMM for next iteration ----
        f32x4 qa[4];
        #pragma unroll
        for (int j = 0; j < 4; ++j) qa[j] = ZERO4;
        #pragma unroll 1
        for (int kc = 0; kc < 8; ++kc) {
            s16x8 a = *reinterpret_cast<const s16x8*>(mls + l15 * 264 + kc * 32 + quad * 8);
            #pragma unroll
            for (int fn = 0; fn < 4; ++fn) {
                s16x8 bv = *reinterpret_cast<const s16x8*>(WqP + (wid * 64 + fn * 16 + l15) * 256 + kc * 32 + quad * 8);
                qa[fn] = mfma16(a, bv, qa[fn]);
            }
        }
        #pragma unroll
        for (int fn = 0; fn < 4; ++fn)
            #pragma unroll
            for (int r = 0; r < 4; ++r) {
                int mt = m0 + quad * 4 + r;
                int d = wid * 64 + fn * 16 + l15;
                qbuf[(b * 64 + mt) * 256 + d] = f2bf(qa[fn][r] * 0.0625f);
            }
    }
}

// ============ kE: attn_out = attnT / colsum; b = blk&7 (XCD-pinned) ============
__global__ void kE(const u16* __restrict__ attnT, const float* __restrict__ colsum,
                   float* __restrict__ out1)
{
    int blk = blockIdx.x;
    int b = blk & 7, r8 = blk >> 3;                  // XCD pin: b = blk%8
    int e = (b << 18) + (r8 << 10) + threadIdx.x * 4;
    int n = (e >> 12) & 63;
    float ci = 1.f / colsum[b * 64 + n];
    const u16* s = attnT + e;
    f32x4 o;
    o.x = bf2f(s[0]) * ci; o.y = bf2f(s[1]) * ci;
    o.z = bf2f(s[2]) * ci; o.w = bf2f(s[3]) * ci;
    *(f32x4*)(out1 + e) = o;
}

// ============ launch ============
extern "C" void kernel_launch(void* const* d_in, const int* in_sizes, int n_in,
                              void* d_out, int out_size, void* d_ws, size_t ws_size,
                              hipStream_t stream)
{
    const float* x       = (const float*)d_in[0];
    const float* tinit   = (const float*)d_in[1];
    const float* conv_w  = (const float*)d_in[2];
    const float* conv_b  = (const float*)d_in[3];
    const float* Wq      = (const float*)d_in[4];
    const float* Wk      = (const float*)d_in[5];
    const float* Wv      = (const float*)d_in[6];
    const float* ln_in_g = (const float*)d_in[7];
    const float* ln_in_b = (const float*)d_in[8];
    const float* ln_t_g  = (const float*)d_in[9];
    const float* ln_t_b  = (const float*)d_in[10];
    const float* ln_m_g  = (const float*)d_in[11];
    const float* ln_m_b  = (const float*)d_in[12];
    const float* W1      = (const float*)d_in[13];
    const float* b1      = (const float*)d_in[14];
    const float* W2      = (const float*)d_in[15];
    const float* b2      = (const float*)d_in[16];

    char* ws = (char*)d_ws;
    u16* Bp       = (u16*)(ws + 0);          // 2,359,296
    u16* WkvP     = (u16*)(ws + 2359296);    //   262,144
    u16* WqP      = (u16*)(ws + 2621440);    //   131,072
    u16* W1T      = (u16*)(ws + 2752512);    //   262,144
    u16* W2T      = (u16*)(ws + 3014656);    //   262,144
    u16* kbuf     = (u16*)(ws + 3276800);    // 16,777,216
    u16* vT       = (u16*)(ws + 20054016);   // 16,777,216
    u16* qbuf     = (u16*)(ws + 36831232);   //   262,144
    u16* attnT    = (u16*)(ws + 37093376);   // 4,194,304  (written last iter only)
    float* colsum = (float*)(ws + 41287680); //     2,048
    float* tpl    = (float*)(ws + 41289728); //   524,288
    float* delta  = (float*)(ws + 41814016); //   524,288
    float* cs_part= (float*)(ws + 42338304); //    65,536   (total ~42.4 MB)

    float* out0 = (float*)d_out;      // templates_out (8,256,64)
    float* out1 = out0 + 131072;      // attn_out (8,64,16,16,16)

    prepack_kernel<<<2944, 256, 0, stream>>>(conv_w, Wk, Wv, Wq, W1, W2, Bp, WkvP, WqP, W1T, W2T);
    conv_fused<<<512, 512, 0, stream>>>(x, Bp, conv_b, ln_in_g, ln_in_b, WkvP, kbuf, vT);
    kQ<<<8, 256, 0, stream>>>(tinit, tpl, ln_t_g, ln_t_b, WqP, qbuf, delta);
    for (int it = 0; it < 6; ++it) {
        int last = (it == 5) ? 1 : 0;
        kA<<<256, 512, 0, stream>>>(qbuf, kbuf, vT, cs_part, delta, last, attnT);
        kT<<<32, 256, 0, stream>>>(tpl, delta, cs_part, colsum, ln_m_g, ln_m_b, W1T, b1, W2T, b2,
                                   ln_t_g, ln_t_b, WqP, qbuf, last, out0);
    }
    kE<<<2048, 256, 0, stream>>>(attnT, colsum, out1);
}

// Round 6
// 716.752 us; speedup vs baseline: 3.9642x; 1.0451x over previous
//
#include <hip/hip_runtime.h>

typedef unsigned short u16;
typedef short s16x8 __attribute__((ext_vector_type(8)));
typedef float f32x4 __attribute__((ext_vector_type(4)));
typedef float f32x4u __attribute__((ext_vector_type(4), aligned(4)));
typedef unsigned short us4 __attribute__((ext_vector_type(4)));   // 8 B

__device__ __forceinline__ float bf2f(u16 v) {
    return __uint_as_float(((unsigned int)v) << 16);
}
__device__ __forceinline__ u16 f2bf(float f) {
    unsigned int u = __float_as_uint(f);
    u = u + 0x7FFFu + ((u >> 16) & 1u);
    return (u16)(u >> 16);
}
__device__ __forceinline__ f32x4 mfma16(s16x8 a, s16x8 b, f32x4 c) {
    return __builtin_amdgcn_mfma_f32_16x16x32_bf16(a, b, c, 0, 0, 0);
}
#define ZERO4 f32x4{0.f, 0.f, 0.f, 0.f}

// ============ prepack: f32 weights -> bf16 MFMA B-fragment layouts ============
__global__ void prepack_kernel(const float* __restrict__ conv_w, const float* __restrict__ Wk,
                               const float* __restrict__ Wv, const float* __restrict__ Wq,
                               const float* __restrict__ W1, const float* __restrict__ W2,
                               u16* __restrict__ Bp, u16* __restrict__ WkvP, u16* __restrict__ WqP,
                               u16* __restrict__ W1T, u16* __restrict__ W2T)
{
    int idx = blockIdx.x * 256 + threadIdx.x;
    if (idx < 294912) {                       // 256 n * 1152 groups
        int n = idx / 1152, g = idx - n * 1152;
        int ic = g / 9, r = g - ic * 9;
        const float* s = conv_w + n * 3456 + ic * 27 + r * 3;
        u16* d = Bp + n * 4608 + g * 4;
        d[0] = f2bf(s[0]); d[1] = f2bf(s[1]); d[2] = f2bf(s[2]); d[3] = 0;
    } else if (idx < 425984) {                // WkvP 512*256
        int i = idx - 294912;
        int n = i >> 8, c = i & 255;
        WkvP[i] = f2bf((n < 256) ? Wk[c * 256 + n] : Wv[c * 256 + (n - 256)]);
    } else if (idx < 491520) {                // WqP 256*256
        int i = idx - 425984;
        int n = i >> 8, c = i & 255;
        WqP[i] = f2bf(Wq[c * 256 + n]);
    } else if (idx < 622592) {                // W1T 512*256
        int i = idx - 491520;
        int h = i >> 8, c = i & 255;
        W1T[i] = f2bf(W1[c * 512 + h]);
    } else if (idx < 753664) {                // W2T 256*512
        int i = idx - 622592;
        int dd = i >> 9, h = i & 511;
        W2T[i] = f2bf(W2[h * 256 + dd]);
    }
}

// ============ fused conv3d(s2)+bias+ReLU+LN_in + k/v GEMM ============
// grid 512; b = blk&7 (XCD-pinned); block 512 (8 waves); M-tile 64 tokens
// LDS DOUBLE-BUFFERED staging: loads for icc+1 issued before compute of icc;
// one barrier per icc (was 2 + exposed HBM latency per icc).
__global__ __launch_bounds__(512, 4) void conv_fused(
    const float* __restrict__ x, const u16* __restrict__ Bp, const float* __restrict__ conv_b,
    const float* __restrict__ ln_g, const float* __restrict__ ln_b, const u16* __restrict__ WkvP,
    u16* __restrict__ kbuf, u16* __restrict__ vT)
{
    __shared__ __align__(16) char smem[66816];
    u16* slab0  = (u16*)smem;                 // [432 rows][36 iz] u16 = 31104 B
    u16* slab1  = (u16*)(smem + 31104);       // second buffer
    u16* tokbf  = (u16*)smem;                 // alias after conv: [64 m][264 c] = 33792 B
    float* lnred  = (float*)(smem + 62208);   // [8 w][64 m][2] = 4096
    float* lnstat = (float*)(smem + 66304);   // [64 m][2] = 512

    int blk = blockIdx.x;
    int b = blk & 7, ox = (blk >> 5) & 15, oyb = (blk >> 3) & 3;   // XCD pin: b = blk%8
    int tid = threadIdx.x, wid = tid >> 6, lane = tid & 63;
    int quad = lane >> 4, l15 = lane & 15;
    int nbase = wid * 32;                     // conv n-slice: 32 channels/wave

    f32x4 acc[4][2];
    #pragma unroll
    for (int i = 0; i < 4; ++i)
        #pragma unroll
        for (int j = 0; j < 2; ++j) acc[i][j] = ZERO4;

    const u16* bprow0 = Bp + (nbase + l15) * 4608 + quad * 8;
    const u16* bprow1 = bprow0 + 16 * 4608;

    // ---- staging descriptors (invariant across icc; only channel offset moves) ----
    const float* xp[8]; int so8[8]; unsigned wmask = 0;
    #pragma unroll
    for (int u = 0; u < 8; ++u) {
        int s = tid + u * 512;
        so8[u] = -1; xp[u] = x;
        if (s < 3888) {
            int row = s / 9;
            int c = s - row * 9;
            int icl = row / 27;
            int rr = row - icl * 27;
            int ixl = rr / 9;
            int iyl = rr - ixl * 9;
            const float* xr = x + ((size_t)((b * 128 + icl) * 33) + (2 * ox + ixl)) * 1089
                              + (8 * oyb + iyl) * 33;
            if (c < 8) { xp[u] = xr + c * 4; wmask |= (1u << u); }
            else       { xp[u] = xr + 32; }
            so8[u] = row * 36 + c * 4;
        }
    }
    const size_t ICST = 16ull * 35937;        // 16 channels of 33*33*33 floats

    f32x4u tv[8];
#define LOADX(ICC)                                                          \
    {                                                                       \
        _Pragma("unroll")                                                   \
        for (int u = 0; u < 8; ++u) {                                       \
            if (so8[u] >= 0) {                                              \
                const float* p = xp[u] + (size_t)(ICC) * ICST;              \
                if ((wmask >> u) & 1u) tv[u] = *(const f32x4u*)p;           \
                else                   tv[u] = f32x4u{p[0], 0.f, 0.f, 0.f}; \
            }                                                               \
        }                                                                   \
    }
#define STOREX(DST)                                                         \
    {                                                                       \
        _Pragma("unroll")                                                   \
        for (int u = 0; u < 8; ++u) {                                       \
            if (so8[u] >= 0) {                                              \
                us4 w;                                                      \
                w.x = f2bf(tv[u].x); w.y = f2bf(tv[u].y);                   \
                w.z = f2bf(tv[u].z); w.w = f2bf(tv[u].w);                   \
                *(us4*)((DST) + so8[u]) = w;                                \
            }                                                               \
        }                                                                   \
    }

    LOADX(0)
    STOREX(slab0)
    __syncthreads();

    for (int icc = 0; icc < 8; ++icc) {
        const u16* cur = (icc & 1) ? slab1 : slab0;
        u16* nxt = (icc & 1) ? slab0 : slab1;
        if (icc < 7) LOADX(icc + 1)           // in flight during compute below

        const u16* bk0 = bprow0 + icc * 576;
        const u16* bk1 = bprow1 + icc * 576;
        s16x8 bbA[2], bbB[2];
        bbA[0] = *reinterpret_cast<const s16x8*>(bk0);
        bbA[1] = *reinterpret_cast<const s16x8*>(bk1);

#define CONV_STEP(CC, BREG)                                                     \
        {                                                                       \
            int g = (CC) * 8 + quad * 2;                                        \
            int i0 = g / 9, r9 = g - i0 * 9;                                    \
            int kx = r9 / 3, ky = r9 - kx * 3;                                  \
            int base0 = (i0 * 27 + kx * 9 + ky) * 36 + 2 * l15;                 \
            g += 1;                                                             \
            i0 = g / 9; r9 = g - i0 * 9; kx = r9 / 3; ky = r9 - kx * 3;         \
            int base1 = (i0 * 27 + kx * 9 + ky) * 36 + 2 * l15;                 \
            _Pragma("unroll")                                                   \
            for (int fm = 0; fm < 4; ++fm) {                                    \
                union { s16x8 v; ushort2 h[4]; } af;                            \
                const u16* sp0 = cur + base0 + fm * 72;                         \
                const u16* sp1 = cur + base1 + fm * 72;                         \
                af.h[0] = *(const ushort2*)(sp0);                               \
                af.h[1] = *(const ushort2*)(sp0 + 2);                           \
                af.h[2] = *(const ushort2*)(sp1);                               \
                af.h[3] = *(const ushort2*)(sp1 + 2);                           \
                acc[fm][0] = mfma16(af.v, (BREG)[0], acc[fm][0]);               \
                acc[fm][1] = mfma16(af.v, (BREG)[1], acc[fm][1]);               \
            }                                                                   \
        }

        #pragma unroll 1
        for (int c8 = 0; c8 < 18; c8 += 2) {
            bbB[0] = *reinterpret_cast<const s16x8*>(bk0 + (c8 + 1) * 32);
            bbB[1] = *reinterpret_cast<const s16x8*>(bk1 + (c8 + 1) * 32);
            CONV_STEP(c8, bbA)
            if (c8 + 2 < 18) {
                bbA[0] = *reinterpret_cast<const s16x8*>(bk0 + (c8 + 2) * 32);
                bbA[1] = *reinterpret_cast<const s16x8*>(bk1 + (c8 + 2) * 32);
            }
            CONV_STEP(c8 + 1, bbB)
        }
#undef CONV_STEP
        if (icc < 7) STOREX(nxt)
        __syncthreads();
    }
#undef LOADX
#undef STOREX

    // ---- bias + relu ----
    #pragma unroll
    for (int fn = 0; fn < 2; ++fn) {
        float bias = conv_b[nbase + fn * 16 + l15];
        #pragma unroll
        for (int fm = 0; fm < 4; ++fm)
            #pragma unroll
            for (int r = 0; r < 4; ++r)
                acc[fm][fn][r] = fmaxf(acc[fm][fn][r] + bias, 0.f);
    }
    // ---- LN_in ----
    #pragma unroll
    for (int fm = 0; fm < 4; ++fm) {
        #pragma unroll
        for (int r = 0; r < 4; ++r) {
            float s = acc[fm][0][r] + acc[fm][1][r];
            float q2 = acc[fm][0][r] * acc[fm][0][r] + acc[fm][1][r] * acc[fm][1][r];
            #pragma unroll
            for (int msk = 1; msk <= 8; msk <<= 1) {
                s  += __shfl_xor(s, msk, 64);
                q2 += __shfl_xor(q2, msk, 64);
            }
            if (l15 == 0) {
                int mm = fm * 16 + quad * 4 + r;
                lnred[(wid * 64 + mm) * 2 + 0] = s;
                lnred[(wid * 64 + mm) * 2 + 1] = q2;
            }
        }
    }
    __syncthreads();
    if (tid < 64) {
        float s = 0, q2 = 0;
        #pragma unroll
        for (int w = 0; w < 8; ++w) { s += lnred[(w * 64 + tid) * 2]; q2 += lnred[(w * 64 + tid) * 2 + 1]; }
        float mu = s * (1.f / 256.f);
        float var = fmaxf(q2 * (1.f / 256.f) - mu * mu, 0.f);
        lnstat[tid * 2]     = mu;
        lnstat[tid * 2 + 1] = rsqrtf(var + 1e-5f);
    }
    __syncthreads();
    {
        float gam[2], bet[2];
        #pragma unroll
        for (int fn = 0; fn < 2; ++fn) {
            int n = nbase + fn * 16 + l15;
            gam[fn] = ln_g[n]; bet[fn] = ln_b[n];
        }
        #pragma unroll
        for (int fm = 0; fm < 4; ++fm)
            #pragma unroll
            for (int r = 0; r < 4; ++r) {
                int mm = fm * 16 + quad * 4 + r;
                float mu = lnstat[mm * 2], rs = lnstat[mm * 2 + 1];
                #pragma unroll
                for (int fn = 0; fn < 2; ++fn) {
                    int n = nbase + fn * 16 + l15;
                    tokbf[mm * 264 + n] = f2bf((acc[fm][fn][r] - mu) * rs * gam[fn] + bet[fn]);
                }
            }
    }
    __syncthreads();
    // ---- k/v GEMM: [64 m]x[512 n], K=256; each wave owns 64 n for all m ----
    f32x4 kacc[4][4];
    #pragma unroll
    for (int i = 0; i < 4; ++i)
        #pragma unroll
        for (int j = 0; j < 4; ++j) kacc[i][j] = ZERO4;
    int n2 = wid * 64;
    const u16* wp = WkvP + (n2 + l15) * 256 + quad * 8;
    s16x8 wvA[4], wvB[4];
    #pragma unroll
    for (int fn = 0; fn < 4; ++fn) wvA[fn] = *reinterpret_cast<const s16x8*>(wp + fn * 4096);

#define KV_STEP(KK, WREG)                                                           \
    {                                                                               \
        s16x8 a2[4];                                                                \
        _Pragma("unroll")                                                           \
        for (int fm = 0; fm < 4; ++fm)                                              \
            a2[fm] = *reinterpret_cast<const s16x8*>(tokbf + (fm * 16 + l15) * 264  \
                                                     + (KK) * 32 + quad * 8);       \
        _Pragma("unroll")                                                           \
        for (int fn = 0; fn < 4; ++fn)                                              \
            _Pragma("unroll")                                                       \
            for (int fm = 0; fm < 4; ++fm)                                          \
                kacc[fm][fn] = mfma16(a2[fm], (WREG)[fn], kacc[fm][fn]);            \
    }

    #pragma unroll 1
    for (int kc = 0; kc < 8; kc += 2) {
        #pragma unroll
        for (int fn = 0; fn < 4; ++fn)
            wvB[fn] = *reinterpret_cast<const s16x8*>(wp + fn * 4096 + (kc + 1) * 32);
        KV_STEP(kc, wvA)
        if (kc + 2 < 8) {
            #pragma unroll
            for (int fn = 0; fn < 4; ++fn)
                wvA[fn] = *reinterpret_cast<const s16x8*>(wp + fn * 4096 + (kc + 2) * 32);
        }
        KV_STEP(kc + 1, wvB)
    }
#undef KV_STEP

    #pragma unroll
    for (int fm = 0; fm < 4; ++fm)
        #pragma unroll
        for (int r = 0; r < 4; ++r) {
            int l = (ox * 16 + oyb * 4 + fm) * 16 + quad * 4 + r;
            #pragma unroll
            for (int fn = 0; fn < 4; ++fn) {
                int n = n2 + fn * 16 + l15;
                u16 v = f2bf(kacc[fm][fn][r]);
                if (n < 256) kbuf[((b << 12) + l) * 256 + n] = v;           // k[b][l][d]
                else         vT[((b * 256 + (n - 256)) << 12) + l] = v;     // vT[b][d][l]
            }
        }
}

// ============ kQ: init tpl; LN_t + q (iter 0); zero delta ============
__global__ __launch_bounds__(256) void kQ(
    const float* __restrict__ tinit, float* __restrict__ tpl,
    const float* __restrict__ ln_t_g, const float* __restrict__ ln_t_b,
    const u16* __restrict__ WqP, u16* __restrict__ qbuf, float* __restrict__ delta)
{
    __shared__ __align__(16) u16 mls[64 * 264];
    __shared__ float pls[64][4][2];
    __shared__ float stat[64][2];
    int b = blockIdx.x, tid = threadIdx.x;
    int m = tid >> 2, part = tid & 3;
    const float* tp = tinit + m * 256 + part * 64;
    float* tg = tpl + (b * 64 + m) * 256 + part * 64;
    float s = 0, q2 = 0;
    for (int i = 0; i < 64; ++i) {
        float v = tp[i];
        tg[i] = v;
        s += v; q2 += v * v;
    }
    pls[m][part][0] = s; pls[m][part][1] = q2;
    __syncthreads();
    if (tid < 64) {
        float ss = 0, qq = 0;
        #pragma unroll
        for (int p = 0; p < 4; ++p) { ss += pls[tid][p][0]; qq += pls[tid][p][1]; }
        float mu = ss * (1.f / 256.f);
        float var = fmaxf(qq * (1.f / 256.f) - mu * mu, 0.f);
        stat[tid][0] = mu; stat[tid][1] = rsqrtf(var + 1e-5f);
    }
    __syncthreads();
    {
        float mu = stat[m][0], rs = stat[m][1];
        for (int i = 0; i < 64; ++i) {
            int d = part * 64 + i;
            mls[m * 264 + d] = f2bf((tp[i] - mu) * rs * ln_t_g[d] + ln_t_b[d]);
        }
    }
    __syncthreads();
    int wid = tid >> 6, lane = tid & 63, quad = lane >> 4, l15 = lane & 15;
    f32x4 qa[4][4];
    #pragma unroll
    for (int i = 0; i < 4; ++i)
        #pragma unroll
        for (int j = 0; j < 4; ++j) qa[i][j] = ZERO4;
    #pragma unroll 1
    for (int kc = 0; kc < 8; ++kc) {
        s16x8 a[4];
        #pragma unroll
        for (int fm = 0; fm < 4; ++fm)
            a[fm] = *reinterpret_cast<const s16x8*>(mls + (fm * 16 + l15) * 264 + kc * 32 + quad * 8);
        #pragma unroll
        for (int fn = 0; fn < 4; ++fn) {
            s16x8 bv = *reinterpret_cast<const s16x8*>(WqP + (wid * 64 + fn * 16 + l15) * 256 + kc * 32 + quad * 8);
            #pragma unroll
            for (int fm = 0; fm < 4; ++fm)
                qa[fm][fn] = mfma16(a[fm], bv, qa[fm][fn]);
        }
    }
    #pragma unroll
    for (int fm = 0; fm < 4; ++fm)
        #pragma unroll
        for (int fn = 0; fn < 4; ++fn)
            #pragma unroll
            for (int r = 0; r < 4; ++r) {
                int mt = fm * 16 + quad * 4 + r;
                int d = wid * 64 + fn * 16 + l15;
                qbuf[(b * 64 + mt) * 256 + d] = f2bf(qa[fm][fn][r] * 0.0625f);
            }
    // zero delta[b] for iter-0 atomics
    f32x4* dz = (f32x4*)(delta + b * 16384);
    for (int i = tid; i < 4096; i += 256) dz[i] = ZERO4;
}

// ============ kA: fused logits+softmax+PV; grid 256; b = blk&7 (XCD-pinned) ============
// vT loads hoisted before phase A (latency hidden under staging+QK^T+softmax).
__global__ __launch_bounds__(512, 2) void kA(
    const u16* __restrict__ qbuf, const u16* __restrict__ kbuf, const u16* __restrict__ vT,
    float* __restrict__ cs_part, float* __restrict__ delta, int last, u16* __restrict__ attnT)
{
    __shared__ __align__(16) u16 qls[64 * 264];       // 33792 B
    __shared__ __align__(16) u16 atile[64 * 136];     // 17408 B [n][l_local]
    __shared__ float colsh[8][64];                    // 2048 B
    int b = blockIdx.x & 7, ltg = blockIdx.x >> 3;    // XCD pin: b = blk%8
    int tid = threadIdx.x, wid = tid >> 6, lane = tid & 63;
    int quad = lane >> 4, l15 = lane & 15;

    // ---- stage q[b] (32 KB) into LDS ----
    {
        int r = tid >> 3, c = (tid & 7) * 32;
        const u16* src = qbuf + b * 16384 + r * 256 + c;
        u16* dst = qls + r * 264 + c;
        #pragma unroll
        for (int j = 0; j < 4; ++j)
            *(int4*)(dst + j * 8) = *(const int4*)(src + j * 8);
    }
    // ---- issue all k-row loads up-front ----
    int lrow = ltg * 128 + wid * 16;
    const u16* arow = kbuf + (size_t)((b << 12) + lrow + l15) * 256;
    s16x8 av[8];
    #pragma unroll
    for (int kc = 0; kc < 8; ++kc)
        av[kc] = *reinterpret_cast<const s16x8*>(arow + kc * 32 + quad * 8);
    // ---- issue vT loads for phase B now (hide latency under phase A) ----
    const u16* vrow = vT + ((size_t)(b * 256 + wid * 32 + l15) << 12) + ltg * 128 + quad * 8;
    s16x8 bv2[2][4];
    #pragma unroll
    for (int fn = 0; fn < 2; ++fn)
        #pragma unroll
        for (int kc = 0; kc < 4; ++kc)
            bv2[fn][kc] = *reinterpret_cast<const s16x8*>(vrow + (fn << 16) + kc * 32);
    __syncthreads();
    // ---- Phase A: QK^T + softmax(N) ----
    f32x4 sa[4];
    #pragma unroll
    for (int fn = 0; fn < 4; ++fn) sa[fn] = ZERO4;
    #pragma unroll
    for (int kc = 0; kc < 8; ++kc) {
        #pragma unroll
        for (int fn = 0; fn < 4; ++fn) {
            s16x8 bv = *reinterpret_cast<const s16x8*>(qls + (fn * 16 + l15) * 264 + kc * 32 + quad * 8);
            sa[fn] = mfma16(av[kc], bv, sa[fn]);
        }
    }
    float colp[4] = {0.f, 0.f, 0.f, 0.f};
    #pragma unroll
    for (int r = 0; r < 4; ++r) {
        float mx = fmaxf(fmaxf(sa[0][r], sa[1][r]), fmaxf(sa[2][r], sa[3][r]));
        #pragma unroll
        for (int msk = 1; msk <= 8; msk <<= 1) mx = fmaxf(mx, __shfl_xor(mx, msk, 64));
        float e[4], sum = 0;
        #pragma unroll
        for (int fn = 0; fn < 4; ++fn) { e[fn] = __expf(sa[fn][r] - mx); sum += e[fn]; }
        #pragma unroll
        for (int msk = 1; msk <= 8; msk <<= 1) sum += __shfl_xor(sum, msk, 64);
        float inv = 1.f / sum;
        #pragma unroll
        for (int fn = 0; fn < 4; ++fn) {
            float p = e[fn] * inv + 1e-8f;
            colp[fn] += p;
            atile[(fn * 16 + l15) * 136 + wid * 16 + quad * 4 + r] = f2bf(p);
        }
    }
    #pragma unroll
    for (int fn = 0; fn < 4; ++fn) {
        float c = colp[fn];
        c += __shfl_xor(c, 16, 64);
        c += __shfl_xor(c, 32, 64);
        if (lane < 16) colsh[wid][fn * 16 + lane] = c;
    }
    __syncthreads();
    if (tid < 64) {
        float s = 0;
        #pragma unroll
        for (int w = 0; w < 8; ++w) s += colsh[w][tid];
        cs_part[((b << 5) + ltg) * 64 + tid] = s;
    }
    // ---- Phase B: PV, K = this block's 128 l; atomics into delta ----
    {
        f32x4 pacc[4][2];
        #pragma unroll
        for (int i = 0; i < 4; ++i)
            #pragma unroll
            for (int j = 0; j < 2; ++j) pacc[i][j] = ZERO4;
        #pragma unroll
        for (int kc = 0; kc < 4; ++kc) {
            #pragma unroll
            for (int fm = 0; fm < 4; ++fm) {
                s16x8 a = *reinterpret_cast<const s16x8*>(atile + (fm * 16 + l15) * 136 + kc * 32 + quad * 8);
                #pragma unroll
                for (int fn = 0; fn < 2; ++fn)
                    pacc[fm][fn] = mfma16(a, bv2[fn][kc], pacc[fm][fn]);
            }
        }
        #pragma unroll
        for (int fm = 0; fm < 4; ++fm)
            #pragma unroll
            for (int fn = 0; fn < 2; ++fn)
                #pragma unroll
                for (int r = 0; r < 4; ++r) {
                    int n = fm * 16 + quad * 4 + r;
                    int d = wid * 32 + fn * 16 + l15;
                    atomicAdd(&delta[(size_t)(b * 64 + n) * 256 + d], pacc[fm][fn][r]);
                }
    }
    // ---- Phase C: P tile -> attnT on last iter only ----
    if (last) {
        int n = tid >> 3, lo = (tid & 7) * 16;
        const u16* src = atile + n * 136 + lo;
        u16* dst = attnT + (size_t)((b * 64 + n) << 12) + ltg * 128 + lo;
        *(int4*)(dst)     = *(const int4*)(src);
        *(int4*)(dst + 8) = *(const int4*)(src + 8);
    }
}

// ============ kT: tpl += delta/colsum (then zero delta); LN_m; MLP; LN_t + q ============
// grid 32; b = blk&7 (XCD-pinned); 16 templates per block; 512 threads (8 waves, 2x TLP)
__global__ __launch_bounds__(512) void kT(
    float* __restrict__ tpl, float* __restrict__ delta, const float* __restrict__ cs_part,
    float* __restrict__ colsum,
    const float* __restrict__ ln_m_g, const float* __restrict__ ln_m_b,
    const u16* __restrict__ W1T, const float* __restrict__ b1,
    const u16* __restrict__ W2T, const float* __restrict__ b2,
    const float* __restrict__ ln_t_g, const float* __restrict__ ln_t_b,
    const u16* __restrict__ WqP, u16* __restrict__ qbuf,
    int last, float* __restrict__ out0)
{
    __shared__ __align__(16) u16 mls[16 * 264];      // 8448
    __shared__ __align__(16) u16 hid[16 * 520];      // 16640
    __shared__ float pls[16][32][2];                 // 4096
    __shared__ float stat[16][2];
    __shared__ float lnr2[8][16][2];                 // 1024
    __shared__ float csh[16];
    int b = blockIdx.x & 7, mg = blockIdx.x >> 3;    // XCD pin: b = blk%8
    int m0 = mg * 16;
    int tid = threadIdx.x, wid = tid >> 6, lane = tid & 63;
    int quad = lane >> 4, l15 = lane & 15;
    // ---- phase 0: reduce colsum partials ----
    if (tid < 16) {
        float s = 0;
        #pragma unroll
        for (int g = 0; g < 32; ++g) s += cs_part[((b << 5) + g) * 64 + m0 + tid];
        csh[tid] = 1.f / s;
        if (last) colsum[b * 64 + m0 + tid] = s;
    }
    __syncthreads();
    // ---- phase 1: v = tpl + delta/colsum; zero delta; LN_m -> mls; tpl = v ----
    {
        int ml = tid >> 5, part = tid & 31;
        float cinv = csh[ml];
        float* tg = tpl + (b * 64 + m0 + ml) * 256 + part * 8;
        float* dg = delta + (size_t)(b * 64 + m0 + ml) * 256 + part * 8;
        float vbuf[8];
        float s = 0, q2 = 0;
        #pragma unroll
        for (int i = 0; i < 8; ++i) {
            float v = tg[i] + dg[i] * cinv;
            vbuf[i] = v; s += v; q2 += v * v;
        }
        if (!last) {
            f32x4* dz = (f32x4*)dg;
            dz[0] = ZERO4; dz[1] = ZERO4;
        }
        pls[ml][part][0] = s; pls[ml][part][1] = q2;
        __syncthreads();
        if (tid < 16) {
            float ss = 0, qq = 0;
            #pragma unroll
            for (int p = 0; p < 32; ++p) { ss += pls[tid][p][0]; qq += pls[tid][p][1]; }
            float mu = ss * (1.f / 256.f);
            float var = fmaxf(qq * (1.f / 256.f) - mu * mu, 0.f);
            stat[tid][0] = mu; stat[tid][1] = rsqrtf(var + 1e-5f);
        }
        __syncthreads();
        float mu = stat[ml][0], rs = stat[ml][1];
        #pragma unroll
        for (int i = 0; i < 8; ++i) {
            int d = part * 8 + i;
            tg[i] = vbuf[i];
            mls[ml * 264 + d] = f2bf((vbuf[i] - mu) * rs * ln_m_g[d] + ln_m_b[d]);
        }
    }
    __syncthreads();
    // ---- G1: hid = gelu(mls @ W1 + b1); 8 waves, wave -> 64 nh ----
    {
        f32x4 ha[4];
        #pragma unroll
        for (int j = 0; j < 4; ++j) ha[j] = ZERO4;
        #pragma unroll 1
        for (int kc = 0; kc < 8; ++kc) {
            s16x8 a = *reinterpret_cast<const s16x8*>(mls + l15 * 264 + kc * 32 + quad * 8);
            #pragma unroll
            for (int fn = 0; fn < 4; ++fn) {
                s16x8 bv = *reinterpret_cast<const s16x8*>(W1T + (wid * 64 + fn * 16 + l15) * 256 + kc * 32 + quad * 8);
                ha[fn] = mfma16(a, bv, ha[fn]);
            }
        }
        #pragma unroll
        for (int fn = 0; fn < 4; ++fn) {
            int nh = wid * 64 + fn * 16 + l15;
            float bb = b1[nh];
            #pragma unroll
            for (int r = 0; r < 4; ++r) {
                float v = ha[fn][r] + bb;
                v = 0.5f * v * (1.f + erff(v * 0.70710678118654752f));
                hid[(quad * 4 + r) * 520 + nh] = f2bf(v);
            }
        }
    }
    __syncthreads();
    // ---- G2: new = tpl + hid @ W2 + b2; LN_t -> mls; out0 on last; wave -> 32 d ----
    {
        f32x4 oa[2];
        oa[0] = ZERO4; oa[1] = ZERO4;
        #pragma unroll 1
        for (int kc = 0; kc < 16; ++kc) {
            s16x8 a = *reinterpret_cast<const s16x8*>(hid + l15 * 520 + kc * 32 + quad * 8);
            #pragma unroll
            for (int fn = 0; fn < 2; ++fn) {
                s16x8 bv = *reinterpret_cast<const s16x8*>(W2T + (wid * 32 + fn * 16 + l15) * 512 + kc * 32 + quad * 8);
                oa[fn] = mfma16(a, bv, oa[fn]);
            }
        }
        #pragma unroll
        for (int fn = 0; fn < 2; ++fn) {
            int d = wid * 32 + fn * 16 + l15;
            float bb = b2[d];
            #pragma unroll
            for (int r = 0; r < 4; ++r) {
                int mm = quad * 4 + r;
                oa[fn][r] += bb + tpl[(b * 64 + m0 + mm) * 256 + d];
            }
        }
        // LN_t stats: per row, partial over this wave's 32 d
        #pragma unroll
        for (int r = 0; r < 4; ++r) {
            float s = oa[0][r] + oa[1][r];
            float q2 = oa[0][r] * oa[0][r] + oa[1][r] * oa[1][r];
            #pragma unroll
            for (int msk = 1; msk <= 8; msk <<= 1) {
                s  += __shfl_xor(s, msk, 64);
                q2 += __shfl_xor(q2, msk, 64);
            }
            if (l15 == 0) {
                lnr2[wid][quad * 4 + r][0] = s;
                lnr2[wid][quad * 4 + r][1] = q2;
            }
        }
        __syncthreads();
        if (tid < 16) {
            float ss = 0, qq = 0;
            #pragma unroll
            for (int w = 0; w < 8; ++w) { ss += lnr2[w][tid][0]; qq += lnr2[w][tid][1]; }
            float mu = ss * (1.f / 256.f);
            float var = fmaxf(qq * (1.f / 256.f) - mu * mu, 0.f);
            stat[tid][0] = mu; stat[tid][1] = rsqrtf(var + 1e-5f);
        }
        __syncthreads();
        #pragma unroll
        for (int fn = 0; fn < 2; ++fn) {
            int d = wid * 32 + fn * 16 + l15;
            float gg = last ? 0.f : ln_t_g[d];
            float bt = last ? 0.f : ln_t_b[d];
            #pragma unroll
            for (int r = 0; r < 4; ++r) {
                int mm = quad * 4 + r;
                float v = oa[fn][r];
                tpl[(b * 64 + m0 + mm) * 256 + d] = v;
                if (last) {
                    out0[(b * 256 + d) * 64 + m0 + mm] = v;
                } else {
                    mls[mm * 264 + d] = f2bf((v - stat[mm][0]) * stat[mm][1] * gg + bt);
                }
            }
        }
    }
    if (!last) {
        __syncthreads();
        // ---- q-GEMM for next iteration; wave -> 32 d ----
        f32x4 qa[2];
        qa[0] = ZERO4; qa[1] = ZERO4;
        #pragma unroll 1
        for (int kc = 0; kc < 8; ++kc) {
            s16x8 a = *reinterpret_cast<const s16x8*>(mls + l15 * 264 + kc * 32 + quad * 8);
            #pragma unroll
            for (int fn = 0; fn < 2; ++fn) {
                s16x8 bv = *reinterpret_cast<const s16x8*>(WqP + (wid * 32 + fn * 16 + l15) * 256 + kc * 32 + quad * 8);
                qa[fn] = mfma16(a, bv, qa[fn]);
            }
        }
        #pragma unroll
        for (int fn = 0; fn < 2; ++fn)
            #pragma unroll
            for (int r = 0; r < 4; ++r) {
                int mt = m0 + quad * 4 + r;
                int d = wid * 32 + fn * 16 + l15;
                qbuf[(b * 64 + mt) * 256 + d] = f2bf(qa[fn][r] * 0.0625f);
            }
    }
}

// ============ kE: attn_out = attnT / colsum; b = blk&7 (XCD-pinned) ============
__global__ void kE(const u16* __restrict__ attnT, const float* __restrict__ colsum,
                   float* __restrict__ out1)
{
    int blk = blockIdx.x;
    int b = blk & 7, r8 = blk >> 3;                  // XCD pin: b = blk%8
    int e = (b << 18) + (r8 << 10) + threadIdx.x * 4;
    int n = (e >> 12) & 63;
    float ci = 1.f / colsum[b * 64 + n];
    const u16* s = attnT + e;
    f32x4 o;
    o.x = bf2f(s[0]) * ci; o.y = bf2f(s[1]) * ci;
    o.z = bf2f(s[2]) * ci; o.w = bf2f(s[3]) * ci;
    *(f32x4*)(out1 + e) = o;
}

// ============ launch ============
extern "C" void kernel_launch(void* const* d_in, const int* in_sizes, int n_in,
                              void* d_out, int out_size, void* d_ws, size_t ws_size,
                              hipStream_t stream)
{
    const float* x       = (const float*)d_in[0];
    const float* tinit   = (const float*)d_in[1];
    const float* conv_w  = (const float*)d_in[2];
    const float* conv_b  = (const float*)d_in[3];
    const float* Wq      = (const float*)d_in[4];
    const float* Wk      = (const float*)d_in[5];
    const float* Wv      = (const float*)d_in[6];
    const float* ln_in_g = (const float*)d_in[7];
    const float* ln_in_b = (const float*)d_in[8];
    const float* ln_t_g  = (const float*)d_in[9];
    const float* ln_t_b  = (const float*)d_in[10];
    const float* ln_m_g  = (const float*)d_in[11];
    const float* ln_m_b  = (const float*)d_in[12];
    const float* W1      = (const float*)d_in[13];
    const float* b1      = (const float*)d_in[14];
    const float* W2      = (const float*)d_in[15];
    const float* b2      = (const float*)d_in[16];

    char* ws = (char*)d_ws;
    u16* Bp       = (u16*)(ws + 0);          // 2,359,296
    u16* WkvP     = (u16*)(ws + 2359296);    //   262,144
    u16* WqP      = (u16*)(ws + 2621440);    //   131,072
    u16* W1T      = (u16*)(ws + 2752512);    //   262,144
    u16* W2T      = (u16*)(ws + 3014656);    //   262,144
    u16* kbuf     = (u16*)(ws + 3276800);    // 16,777,216
    u16* vT       = (u16*)(ws + 20054016);   // 16,777,216
    u16* qbuf     = (u16*)(ws + 36831232);   //   262,144
    u16* attnT    = (u16*)(ws + 37093376);   // 4,194,304  (written last iter only)
    float* colsum = (float*)(ws + 41287680); //     2,048
    float* tpl    = (float*)(ws + 41289728); //   524,288
    float* delta  = (float*)(ws + 41814016); //   524,288
    float* cs_part= (float*)(ws + 42338304); //    65,536   (total ~42.4 MB)

    float* out0 = (float*)d_out;      // templates_out (8,256,64)
    float* out1 = out0 + 131072;      // attn_out (8,64,16,16,16)

    prepack_kernel<<<2944, 256, 0, stream>>>(conv_w, Wk, Wv, Wq, W1, W2, Bp, WkvP, WqP, W1T, W2T);
    conv_fused<<<512, 512, 0, stream>>>(x, Bp, conv_b, ln_in_g, ln_in_b, WkvP, kbuf, vT);
    kQ<<<8, 256, 0, stream>>>(tinit, tpl, ln_t_g, ln_t_b, WqP, qbuf, delta);
    for (int it = 0; it < 6; ++it) {
        int last = (it == 5) ? 1 : 0;
        kA<<<256, 512, 0, stream>>>(qbuf, kbuf, vT, cs_part, delta, last, attnT);
        kT<<<32, 512, 0, stream>>>(tpl, delta, cs_part, colsum, ln_m_g, ln_m_b, W1T, b1, W2T, b2,
                                   ln_t_g, ln_t_b, WqP, qbuf, last, out0);
    }
    kE<<<2048, 256, 0, stream>>>(attnT, colsum, out1);
}